// Round 1
// baseline (58459.473 us; speedup 1.0000x reference)
//
#include <hip/hip_runtime.h>
#include <math.h>

// Problem constants
#define BB  8
#define CH  256
#define VV  96
#define TT  96
#define NVT (VV*TT)      // 9216
#define C8V 32           // C/8
#define C2V 128          // C/2

// -------------------------------------------------------------------------
// Direct 3x3 conv, pad 1, no bias. One output element per thread.
// Block = 256 threads; NVT=9216 is a multiple of 256, so every block has a
// single (b, co) -> weights staged once in LDS.
// -------------------------------------------------------------------------
__global__ __launch_bounds__(256) void conv3x3_k(
    const float* __restrict__ x, const float* __restrict__ w,
    float* __restrict__ y, int Cin, int Cout)
{
    __shared__ float sw[256 * 9];
    int idx = blockIdx.x * 256 + threadIdx.x;
    int t  = idx % TT;
    int v  = (idx / TT) % VV;
    int bc = idx / NVT;
    int co = bc % Cout;
    int b  = bc / Cout;

    for (int i = threadIdx.x; i < Cin * 9; i += 256)
        sw[i] = w[(size_t)co * Cin * 9 + i];
    __syncthreads();

    // Precompute the 9 tap offsets + 0/1 masks (boundary handling w/o branches)
    float msk[9];
    int   off[9];
#pragma unroll
    for (int kh = 0; kh < 3; ++kh)
#pragma unroll
        for (int kw = 0; kw < 3; ++kw) {
            int v2 = v + kh - 1, t2 = t + kw - 1;
            bool ok = (v2 >= 0) && (v2 < VV) && (t2 >= 0) && (t2 < TT);
            msk[kh * 3 + kw] = ok ? 1.f : 0.f;
            off[kh * 3 + kw] = ok ? (v2 * TT + t2) : 0;
        }

    const float* xb = x + (size_t)b * Cin * NVT;
    float acc = 0.f;
    for (int ci = 0; ci < Cin; ++ci) {
        const float* xc = xb + (size_t)ci * NVT;
        const float* ww = sw + ci * 9;
#pragma unroll
        for (int k2 = 0; k2 < 9; ++k2)
            acc = fmaf(xc[off[k2]] * msk[k2], ww[k2], acc);
    }
    y[idx] = acc;
}

// -------------------------------------------------------------------------
// 3x3 conv (Cin -> 256) of av, scaled by sigma, accumulated into out.
// If xadd != nullptr: out = xadd + sigma*conv  else out += sigma*conv.
// -------------------------------------------------------------------------
__global__ __launch_bounds__(256) void conv3_accum_k(
    const float* __restrict__ av, const float* __restrict__ w,
    const float* __restrict__ sig, const float* __restrict__ xadd,
    float* __restrict__ out, int Cin)
{
    __shared__ float sw[256 * 9];
    int idx = blockIdx.x * 256 + threadIdx.x;
    int t  = idx % TT;
    int v  = (idx / TT) % VV;
    int bc = idx / NVT;
    int co = bc % CH;
    int b  = bc / CH;

    for (int i = threadIdx.x; i < Cin * 9; i += 256)
        sw[i] = w[(size_t)co * Cin * 9 + i];
    __syncthreads();

    float msk[9];
    int   off[9];
#pragma unroll
    for (int kh = 0; kh < 3; ++kh)
#pragma unroll
        for (int kw = 0; kw < 3; ++kw) {
            int v2 = v + kh - 1, t2 = t + kw - 1;
            bool ok = (v2 >= 0) && (v2 < VV) && (t2 >= 0) && (t2 < TT);
            msk[kh * 3 + kw] = ok ? 1.f : 0.f;
            off[kh * 3 + kw] = ok ? (v2 * TT + t2) : 0;
        }

    const float* xb = av + (size_t)b * Cin * NVT;
    float acc = 0.f;
    for (int ci = 0; ci < Cin; ++ci) {
        const float* xc = xb + (size_t)ci * NVT;
        const float* ww = sw + ci * 9;
#pragma unroll
        for (int k2 = 0; k2 < 9; ++k2)
            acc = fmaf(xc[off[k2]] * msk[k2], ww[k2], acc);
    }
    float s    = sig[0];
    float base = xadd ? xadd[idx] : out[idx];
    out[idx] = fmaf(s, acc, base);
}

// -------------------------------------------------------------------------
// 1x1 conv with bias, Cin=Cout=256 (cAttn q/k/v).
// -------------------------------------------------------------------------
__global__ __launch_bounds__(256) void conv1x1_k(
    const float* __restrict__ x, const float* __restrict__ w,
    const float* __restrict__ bias, float* __restrict__ y)
{
    __shared__ float sw[CH];
    int idx = blockIdx.x * 256 + threadIdx.x;
    int pos = idx % NVT;
    int bc  = idx / NVT;
    int co  = bc % CH;
    int b   = bc / CH;

    sw[threadIdx.x] = w[(size_t)co * CH + threadIdx.x];
    __syncthreads();

    const float* xb = x + (size_t)b * CH * NVT + pos;
    float acc = bias[co];
    for (int ci = 0; ci < CH; ++ci)
        acc = fmaf(xb[(size_t)ci * NVT], sw[ci], acc);
    y[idx] = acc;
}

// -------------------------------------------------------------------------
// vAttn / tAttn: one block per (b, p) where p = t (OVER_V) or v (!OVER_V).
// Sequence length 96, qk channels 32, v channels 128.
//   scores[r,w] = sum_c q[c,r]*k[c,w];  softmax over w;
//   av[c,r]     = sum_w a[r,w]*v[c,w]
// -------------------------------------------------------------------------
template <bool OVER_V>
__global__ __launch_bounds__(256) void attn_small_k(
    const float* __restrict__ q, const float* __restrict__ k,
    const float* __restrict__ vv, float* __restrict__ av)
{
    __shared__ float uqk[2 * C8V * 96];   // q then k; reused for v chunks (64x96)
    __shared__ float sc[96][97];          // scores, padded stride

    int b = blockIdx.x / 96;
    int p = blockIdx.x % 96;

    // load q,k tiles [32][96]
    for (int n = threadIdx.x; n < C8V * 96; n += 256) {
        int c = n / 96, i = n % 96;
        size_t o = ((size_t)(b * C8V + c) * VV + (OVER_V ? i : p)) * TT + (OVER_V ? p : i);
        uqk[n]            = q[o];
        uqk[C8V * 96 + n] = k[o];
    }
    __syncthreads();

    // scores
    for (int n = threadIdx.x; n < 96 * 96; n += 256) {
        int r = n / 96, wc = n % 96;
        float acc = 0.f;
#pragma unroll
        for (int c = 0; c < C8V; ++c)
            acc = fmaf(uqk[c * 96 + r], uqk[C8V * 96 + c * 96 + wc], acc);
        sc[r][wc] = acc;
    }
    __syncthreads();

    // softmax per row (96 rows, serial per thread; cheap vs the matmuls)
    if (threadIdx.x < 96) {
        int r = threadIdx.x;
        float m = -1e30f;
        for (int j = 0; j < 96; ++j) m = fmaxf(m, sc[r][j]);
        float ssum = 0.f;
        for (int j = 0; j < 96; ++j) { float e = expf(sc[r][j] - m); sc[r][j] = e; ssum += e; }
        float inv = 1.f / ssum;
        for (int j = 0; j < 96; ++j) sc[r][j] *= inv;
    }
    __syncthreads();

    // av, two 64-channel chunks of V staged into uqk
    for (int cc = 0; cc < 2; ++cc) {
        for (int n = threadIdx.x; n < 64 * 96; n += 256) {
            int c = n / 96, i = n % 96;
            size_t o = ((size_t)(b * C2V + cc * 64 + c) * VV + (OVER_V ? i : p)) * TT + (OVER_V ? p : i);
            uqk[n] = vv[o];
        }
        __syncthreads();
        for (int n = threadIdx.x; n < 64 * 96; n += 256) {
            int c = n / 96, i = n % 96;
            float acc = 0.f;
            for (int wc = 0; wc < 96; ++wc)
                acc = fmaf(sc[i][wc], uqk[c * 96 + wc], acc);
            size_t o = ((size_t)(b * C2V + cc * 64 + c) * VV + (OVER_V ? i : p)) * TT + (OVER_V ? p : i);
            av[o] = acc;
        }
        __syncthreads();
    }
}

// -------------------------------------------------------------------------
// cAttn: attention over the 256 channels, per (b,v), contracting over t.
// One block per (b, v, 32-row chunk cc).
//   scores[c,d] = sum_t q[c,t]*k[d,t]; softmax over d; av[c,t]=sum_d a[c,d]*v[d,t]
// -------------------------------------------------------------------------
__global__ __launch_bounds__(256) void attn_chan_k(
    const float* __restrict__ q, const float* __restrict__ k,
    const float* __restrict__ vv, float* __restrict__ av)
{
    __shared__ float sq[32][97];
    __shared__ float sk[32][97];     // staging for k chunks, then v chunks
    __shared__ float sc[32][257];

    int cc = blockIdx.x % 8;
    int v  = (blockIdx.x / 8) % VV;
    int b  = blockIdx.x / (8 * VV);

    for (int n = threadIdx.x; n < 32 * 96; n += 256) {
        int c = n / 96, t = n % 96;
        sq[c][t] = q[((size_t)(b * CH + cc * 32 + c) * VV + v) * TT + t];
    }
    __syncthreads();

    // scores in 8 chunks of 32 d-columns
    for (int dch = 0; dch < 8; ++dch) {
        for (int n = threadIdx.x; n < 32 * 96; n += 256) {
            int d = n / 96, t = n % 96;
            sk[d][t] = k[((size_t)(b * CH + dch * 32 + d) * VV + v) * TT + t];
        }
        __syncthreads();
        for (int n = threadIdx.x; n < 32 * 32; n += 256) {
            int cl = n / 32, dl = n % 32;
            float acc = 0.f;
            for (int t = 0; t < 96; ++t)
                acc = fmaf(sq[cl][t], sk[dl][t], acc);
            sc[cl][dch * 32 + dl] = acc;
        }
        __syncthreads();
    }

    // softmax per row over 256
    if (threadIdx.x < 32) {
        int r = threadIdx.x;
        float m = -1e30f;
        for (int j = 0; j < 256; ++j) m = fmaxf(m, sc[r][j]);
        float ssum = 0.f;
        for (int j = 0; j < 256; ++j) { float e = expf(sc[r][j] - m); sc[r][j] = e; ssum += e; }
        float inv = 1.f / ssum;
        for (int j = 0; j < 256; ++j) sc[r][j] *= inv;
    }
    __syncthreads();

    // av accumulation over 8 v-chunks; each thread owns 12 outputs of the 32x96 tile
    float acc[12];
#pragma unroll
    for (int j = 0; j < 12; ++j) acc[j] = 0.f;

    for (int dch = 0; dch < 8; ++dch) {
        for (int n = threadIdx.x; n < 32 * 96; n += 256) {
            int d = n / 96, t = n % 96;
            sk[d][t] = vv[((size_t)(b * CH + dch * 32 + d) * VV + v) * TT + t];
        }
        __syncthreads();
#pragma unroll
        for (int j = 0; j < 12; ++j) {
            int n  = threadIdx.x + j * 256;
            int cl = n / 96, t = n % 96;
            float a2 = acc[j];
            for (int dl = 0; dl < 32; ++dl)
                a2 = fmaf(sc[cl][dch * 32 + dl], sk[dl][t], a2);
            acc[j] = a2;
        }
        __syncthreads();
    }

#pragma unroll
    for (int j = 0; j < 12; ++j) {
        int n  = threadIdx.x + j * 256;
        int cl = n / 96, t = n % 96;
        av[((size_t)(b * CH + cc * 32 + cl) * VV + v) * TT + t] = acc[j];
    }
}

// -------------------------------------------------------------------------
extern "C" void kernel_launch(void* const* d_in, const int* in_sizes, int n_in,
                              void* d_out, int out_size, void* d_ws, size_t ws_size,
                              hipStream_t stream)
{
    const float* x     = (const float*)d_in[0];
    const float* v_wq  = (const float*)d_in[1];
    const float* v_wk  = (const float*)d_in[2];
    const float* v_wv  = (const float*)d_in[3];
    const float* v_wo  = (const float*)d_in[4];
    const float* v_sig = (const float*)d_in[5];
    const float* t_wq  = (const float*)d_in[6];
    const float* t_wk  = (const float*)d_in[7];
    const float* t_wv  = (const float*)d_in[8];
    const float* t_wo  = (const float*)d_in[9];
    const float* t_sig = (const float*)d_in[10];
    const float* c_wq  = (const float*)d_in[11];
    const float* c_bq  = (const float*)d_in[12];
    const float* c_wk  = (const float*)d_in[13];
    const float* c_bk  = (const float*)d_in[14];
    const float* c_wv  = (const float*)d_in[15];
    const float* c_bv  = (const float*)d_in[16];
    const float* c_wo  = (const float*)d_in[17];
    const float* c_sig = (const float*)d_in[18];

    float* out = (float*)d_out;
    float* ws  = (float*)d_ws;

    // 4 fp32 slots of [8,256,96,96] (cAttn needs q,k,v,av concurrently) = 302 MB
    const size_t SLOT = (size_t)BB * CH * NVT;
    float* p0 = ws;
    float* p1 = ws + SLOT;
    float* p2 = ws + 2 * SLOT;
    float* p3 = ws + 3 * SLOT;

    dim3 blk(256);
    const int gQK = BB * C8V * NVT / 256;   // 9216
    const int gV  = BB * C2V * NVT / 256;   // 36864
    const int gC  = BB * CH  * NVT / 256;   // 73728

    // ---- vAttn ----
    conv3x3_k<<<gQK, blk, 0, stream>>>(x, v_wq, p0, CH, C8V);
    conv3x3_k<<<gQK, blk, 0, stream>>>(x, v_wk, p1, CH, C8V);
    conv3x3_k<<<gV,  blk, 0, stream>>>(x, v_wv, p2, CH, C2V);
    attn_small_k<true><<<BB * TT, blk, 0, stream>>>(p0, p1, p2, p3);
    conv3_accum_k<<<gC, blk, 0, stream>>>(p3, v_wo, v_sig, x, out, C2V);

    // ---- tAttn ----
    conv3x3_k<<<gQK, blk, 0, stream>>>(x, t_wq, p0, CH, C8V);
    conv3x3_k<<<gQK, blk, 0, stream>>>(x, t_wk, p1, CH, C8V);
    conv3x3_k<<<gV,  blk, 0, stream>>>(x, t_wv, p2, CH, C2V);
    attn_small_k<false><<<BB * VV, blk, 0, stream>>>(p0, p1, p2, p3);
    conv3_accum_k<<<gC, blk, 0, stream>>>(p3, t_wo, t_sig, nullptr, out, C2V);

    // ---- cAttn ----
    conv1x1_k<<<gC, blk, 0, stream>>>(x, c_wq, c_bq, p0);
    conv1x1_k<<<gC, blk, 0, stream>>>(x, c_wk, c_bk, p1);
    conv1x1_k<<<gC, blk, 0, stream>>>(x, c_wv, c_bv, p2);
    attn_chan_k<<<BB * VV * 8, blk, 0, stream>>>(p0, p1, p2, p3);
    conv3_accum_k<<<gC, blk, 0, stream>>>(p3, c_wo, c_sig, nullptr, out, CH);
}

// Round 2
// 1568.273 us; speedup vs baseline: 37.2763x; 37.2763x over previous
//
#include <hip/hip_runtime.h>
#include <math.h>

#define BB  8
#define CH  256
#define NVT 9216        // 96*96

typedef short bh8 __attribute__((ext_vector_type(8)));
typedef short bh4 __attribute__((ext_vector_type(4)));
typedef float f4  __attribute__((ext_vector_type(4)));

__device__ __forceinline__ float bf2f(ushort u) {
    union { uint i; float f; } x; x.i = ((uint)u) << 16; return x.f;
}
__device__ __forceinline__ ushort f2bf(float f) {
    union { float f; uint i; } x; x.f = f;
    uint r = (x.i + 0x7FFFu + ((x.i >> 16) & 1u)) >> 16;
    return (ushort)r;
}

// -------------------------------------------------------------------------
// x fp32 -> bf16 compact
// -------------------------------------------------------------------------
__global__ __launch_bounds__(256) void cvt_x_k(const float* __restrict__ x,
                                               ushort* __restrict__ xb, int n)
{
    int i = blockIdx.x * 256 + threadIdx.x;
    if (i < n) xb[i] = f2bf(x[i]);
}

// -------------------------------------------------------------------------
// Pack conv weights [Csrc][CIN][TAPS] fp32 into MFMA A-fragment order bf16.
// dst short idx = (((kc*TAPS+tap)*COT + cot)*64 + lane)*8 + i
// with k-granule: klocal = 16*(i>>2) + 4*(lane>>4) + (i&3), row = lane&15 = co&15
// -------------------------------------------------------------------------
__global__ __launch_bounds__(256) void wpack_k(const float* __restrict__ w,
    ushort* __restrict__ dst, int CIN, int TAPS, int Csrc, int coBase, int COT)
{
    int n = blockIdx.x * 256 + threadIdx.x;
    int total = (CIN >> 5) * TAPS * Csrc * 32;
    if (n >= total) return;
    int kl  = n & 31;
    int rem = n >> 5;
    int col = rem % Csrc; rem /= Csrc;
    int tap = rem % TAPS;
    int kc  = rem / TAPS;
    int ci  = kc * 32 + kl;
    int g   = (kl >> 2) & 3;
    int i   = ((kl >> 4) << 2) | (kl & 3);
    int cog = coBase + col;
    int cot = cog >> 4, lc = cog & 15;
    float v = w[((size_t)col * CIN + ci) * TAPS + tap];
    dst[((((size_t)kc * TAPS + tap) * COT + cot) * 64 + (g * 16 + lc)) * 8 + i] = f2bf(v);
}

// -------------------------------------------------------------------------
// Implicit-GEMM conv via MFMA 16x16x32 bf16.  Block: (v0, b), 256 thr = 4 waves.
// Block tile: COUT x 96t (one v row).  Wave: wc=w&1 co-half, wt=w>>1 t-half(48).
// LDS x-tile: [32ci][ROWS][PITCH], data at elem 2+tc (tc = compact t), zeros at
// borders -> boundary handled by zero staging.  PITCH=116: ci-group stride
// 4*ROWS*116*2 B mod 128 spreads the 4 lane-groups -> conflict-free u16 reads.
// OMODE: 0 = bf16 compact [b][COUT][96][96]
//        2 = bf16 transposed [b][96][96][COUT] (b64 stores)
//        3 = fp32 out[idx] += sig * conv
// -------------------------------------------------------------------------
template<int TAPS, int CT, int OMODE, bool HASBIAS>
__global__ __launch_bounds__(256) void conv_mfma(
    const ushort* __restrict__ xin, const ushort* __restrict__ wpk,
    ushort* __restrict__ obf, float* __restrict__ oacc,
    const float* __restrict__ bias, const float* __restrict__ sig, int CIN)
{
    constexpr int ROWS  = (TAPS == 9) ? 3 : 1;
    constexpr int PITCH = 116;
    constexpr int CSTR  = PITCH * ROWS;
    constexpr int COUT  = CT * 32;
    constexpr int COT   = COUT / 16;
    __shared__ ushort sx[32 * CSTR];

    int v0 = blockIdx.x, b = blockIdx.y;
    int tid = threadIdx.x;
    int w = tid >> 6, l = tid & 63;
    int g = l >> 4, col = l & 15;
    int wc = w & 1, wt = w >> 1;

    f4 acc[CT][3];
#pragma unroll
    for (int ct = 0; ct < CT; ++ct)
#pragma unroll
        for (int nt = 0; nt < 3; ++nt) acc[ct][nt] = (f4){0.f, 0.f, 0.f, 0.f};

    const int KC = CIN >> 5;
    for (int kc = 0; kc < KC; ++kc) {
        if (kc) __syncthreads();
        // ---- stage 32ci x ROWS x (2 zero | 96 data | 2 zero) as u32 slots ----
        for (int s = tid; s < 32 * ROWS * 50; s += 256) {
            int t2 = s % 50, vr = (s / 50) % ROWS, ci = s / (50 * ROWS);
            int row = v0 + vr - ((TAPS == 9) ? 1 : 0);
            uint val = 0;
            int dstp = ci * CSTR + vr * PITCH + ((t2 == 49) ? 98 : (t2 ? 2 * t2 : 0));
            if (t2 >= 1 && t2 <= 48 && row >= 0 && row < 96) {
                const uint* src = (const uint*)(xin +
                    (((size_t)b * CIN + kc * 32 + ci) * 96 + row) * 96);
                val = src[t2 - 1];
            }
            *(uint*)(&sx[dstp]) = val;
        }
        __syncthreads();
#pragma unroll
        for (int tap = 0; tap < TAPS; ++tap) {
            const int kh = (TAPS == 9) ? tap / 3 : 0;
            const int kw = (TAPS == 9) ? tap % 3 : 1;
            bh8 af[CT];
            const bh8* wp = (const bh8*)wpk;
#pragma unroll
            for (int ct = 0; ct < CT; ++ct)
                af[ct] = wp[(((size_t)kc * TAPS + tap) * COT + (wc * CT + ct)) * 64 + l];
#pragma unroll
            for (int nt = 0; nt < 3; ++nt) {
                int tb = wt * 48 + nt * 16 + col + kw - 1;
                int base = kh * PITCH + 2 + tb;
                bh8 bf;
#pragma unroll
                for (int i = 0; i < 8; ++i) {
                    int cil = ((i >> 2) << 4) + (g << 2) + (i & 3);
                    bf[i] = (short)sx[cil * CSTR + base];
                }
#pragma unroll
                for (int ct = 0; ct < CT; ++ct)
                    acc[ct][nt] = __builtin_amdgcn_mfma_f32_16x16x32_bf16(
                        af[ct], bf, acc[ct][nt], 0, 0, 0);
            }
        }
    }

    // ---- epilogue ----
    float sg = 0.f;
    if (OMODE == 3) sg = sig[0];
#pragma unroll
    for (int ct = 0; ct < CT; ++ct) {
#pragma unroll
        for (int nt = 0; nt < 3; ++nt) {
            int tt = wt * 48 + nt * 16 + col;
            if (OMODE == 2) {
                bh4 o;
#pragma unroll
                for (int j = 0; j < 4; ++j) {
                    int cog = (wc * CT + ct) * 16 + g * 4 + j;
                    float val = acc[ct][nt][j];
                    if (HASBIAS) val += bias[cog];
                    o[j] = (short)f2bf(val);
                }
                int cb = (wc * CT + ct) * 16 + g * 4;
                *(bh4*)&obf[(((size_t)b * 96 + v0) * 96 + tt) * COUT + cb] = o;
            } else {
#pragma unroll
                for (int j = 0; j < 4; ++j) {
                    int cog = (wc * CT + ct) * 16 + g * 4 + j;
                    float val = acc[ct][nt][j];
                    if (HASBIAS) val += bias[cog];
                    size_t o = (((size_t)b * COUT + cog) * 96 + v0) * 96 + tt;
                    if (OMODE == 0) obf[o] = f2bf(val);
                    else            oacc[o] += sg * val;
                }
            }
        }
    }
}

// -------------------------------------------------------------------------
// transpose last two dims of [X][96][96] bf16 (for vAttn coalesced loads)
// -------------------------------------------------------------------------
__global__ __launch_bounds__(256) void transpose_vt_k(const ushort* __restrict__ in,
                                                      ushort* __restrict__ out)
{
    __shared__ ushort tile[96][100];
    size_t base = (size_t)blockIdx.x * NVT;
    for (int n = threadIdx.x; n < NVT; n += 256) tile[n / 96][n % 96] = in[base + n];
    __syncthreads();
    for (int n = threadIdx.x; n < NVT; n += 256) out[base + n] = tile[n % 96][n / 96];
}

// -------------------------------------------------------------------------
// vAttn / tAttn core (fp32 VALU, float4-blocked LDS).  One block per (b,p).
// qkv: [b][192][96][96] with dims arranged so element (ch, p, i) is at
// ((b*192+ch)*96+p)*96+i (tAttn: native; vAttn: pre-transposed copy).
// q = ch 0..31, k = 32..63, v = 64..191.  av written compact [b][128][96][96].
// -------------------------------------------------------------------------
template<bool OVER_V>
__global__ __launch_bounds__(256) void attn_vt_k(const ushort* __restrict__ qkv,
                                                 ushort* __restrict__ av)
{
    __shared__ float sQ[96][36];
    __shared__ float sK[96][36];
    __shared__ float sV[32][96];
    __shared__ float sc[96][100];
    int b = blockIdx.x / 96, p = blockIdx.x % 96;
    int tid = threadIdx.x;
    const size_t base = ((size_t)b * 192) * NVT + (size_t)p * 96;

    for (int n = tid; n < 3072; n += 256) {
        int c = n / 96, i = n % 96;
        sQ[i][c] = bf2f(qkv[base + (size_t)c * NVT + i]);
        sK[i][c] = bf2f(qkv[base + (size_t)(c + 32) * NVT + i]);
    }
    __syncthreads();

    // scores: 96r x 96w, blocked 4 w per unit
    for (int u = tid; u < 2304; u += 256) {
        int r = u / 24, w4 = (u % 24) * 4;
        float a0 = 0, a1 = 0, a2 = 0, a3 = 0;
#pragma unroll
        for (int c4 = 0; c4 < 8; ++c4) {
            f4 q  = *(const f4*)&sQ[r][c4 * 4];
            f4 k0 = *(const f4*)&sK[w4 + 0][c4 * 4];
            f4 k1 = *(const f4*)&sK[w4 + 1][c4 * 4];
            f4 k2 = *(const f4*)&sK[w4 + 2][c4 * 4];
            f4 k3 = *(const f4*)&sK[w4 + 3][c4 * 4];
            a0 = fmaf(q.x, k0.x, fmaf(q.y, k0.y, fmaf(q.z, k0.z, fmaf(q.w, k0.w, a0))));
            a1 = fmaf(q.x, k1.x, fmaf(q.y, k1.y, fmaf(q.z, k1.z, fmaf(q.w, k1.w, a1))));
            a2 = fmaf(q.x, k2.x, fmaf(q.y, k2.y, fmaf(q.z, k2.z, fmaf(q.w, k2.w, a2))));
            a3 = fmaf(q.x, k3.x, fmaf(q.y, k3.y, fmaf(q.z, k3.z, fmaf(q.w, k3.w, a3))));
        }
        f4 o = {a0, a1, a2, a3};
        *(f4*)&sc[r][w4] = o;
    }
    __syncthreads();

    if (tid < 96) {
        int r = tid;
        float m = -1e30f;
        for (int j = 0; j < 96; ++j) m = fmaxf(m, sc[r][j]);
        float ssum = 0.f;
        for (int j = 0; j < 96; ++j) { float e = __expf(sc[r][j] - m); sc[r][j] = e; ssum += e; }
        float inv = 1.f / ssum;
        for (int j = 0; j < 96; ++j) sc[r][j] *= inv;
    }
    __syncthreads();

    // av: 4 chunks of 32 channels
    for (int ch = 0; ch < 4; ++ch) {
        if (ch) __syncthreads();
        for (int n = tid; n < 3072; n += 256) {
            int c = n / 96, i = n % 96;
            sV[c][i] = bf2f(qkv[base + (size_t)(64 + ch * 32 + c) * NVT + i]);
        }
        __syncthreads();
        for (int u = tid; u < 768; u += 256) {
            int c = u / 24, i0 = (u % 24) * 4;
            float a[4] = {0.f, 0.f, 0.f, 0.f};
            for (int w4 = 0; w4 < 24; ++w4) {
                f4 vv = *(const f4*)&sV[c][w4 * 4];
#pragma unroll
                for (int m = 0; m < 4; ++m) {
                    f4 s = *(const f4*)&sc[i0 + m][w4 * 4];
                    a[m] = fmaf(s.x, vv.x, fmaf(s.y, vv.y, fmaf(s.z, vv.z, fmaf(s.w, vv.w, a[m]))));
                }
            }
            int cg = ch * 32 + c;
#pragma unroll
            for (int m = 0; m < 4; ++m) {
                int i = i0 + m;
                size_t o = OVER_V ? (((size_t)b * 128 + cg) * 96 + i) * 96 + p
                                  : (((size_t)b * 128 + cg) * 96 + p) * 96 + i;
                av[o] = f2bf(a[m]);
            }
        }
    }
}

// -------------------------------------------------------------------------
// cAttn via MFMA: block per (v, cc, b); 64 c-rows, full 256 d, K over t=96.
// S = Q K^T (contract t), softmax over d in registers, av = P V (contract d).
// -------------------------------------------------------------------------
__global__ __launch_bounds__(256) void attn_c_k(const ushort* __restrict__ qc,
    const ushort* __restrict__ kc_, const ushort* __restrict__ vc,
    ushort* __restrict__ avc)
{
    __shared__ ushort sQ[64 * 104];
    __shared__ ushort sK[256 * 104];
    __shared__ ushort sV[96 * 264];
    __shared__ ushort sP[64 * 264];

    int v = blockIdx.x, cc = blockIdx.y, b = blockIdx.z;
    int c0 = cc * 64;
    int tid = threadIdx.x;
    int w = tid >> 6, l = tid & 63;
    int g = l >> 4, lc = l & 15;

    for (int s = tid; s < 64 * 12; s += 256) {
        int r = s / 12, sg = s % 12;
        *(bh8*)&sQ[r * 104 + sg * 8] =
            *(const bh8*)&qc[(((size_t)b * 256 + c0 + r) * 96 + v) * 96 + sg * 8];
    }
    for (int s = tid; s < 256 * 12; s += 256) {
        int r = s / 12, sg = s % 12;
        *(bh8*)&sK[r * 104 + sg * 8] =
            *(const bh8*)&kc_[(((size_t)b * 256 + r) * 96 + v) * 96 + sg * 8];
    }
    for (int s = tid; s < 96 * 32; s += 256) {
        int r = s / 32, sg = s % 32;
        *(bh8*)&sV[r * 264 + sg * 8] =
            *(const bh8*)&vc[(((size_t)b * 96 + v) * 96 + r) * 256 + sg * 8];
    }
    __syncthreads();

    // ---- scores: wave w owns c-tile w (16 rows), all 256 d ----
    f4 s16[16];
#pragma unroll
    for (int nt = 0; nt < 16; ++nt) s16[nt] = (f4){0.f, 0.f, 0.f, 0.f};
#pragma unroll
    for (int ks = 0; ks < 3; ++ks) {
        bh4 alo = *(const bh4*)&sQ[(w * 16 + lc) * 104 + ks * 32 + 4 * g];
        bh4 ahi = *(const bh4*)&sQ[(w * 16 + lc) * 104 + ks * 32 + 4 * g + 16];
        bh8 aq = __builtin_shufflevector(alo, ahi, 0, 1, 2, 3, 4, 5, 6, 7);
#pragma unroll
        for (int nt = 0; nt < 16; ++nt) {
            bh4 blo = *(const bh4*)&sK[(nt * 16 + lc) * 104 + ks * 32 + 4 * g];
            bh4 bhi = *(const bh4*)&sK[(nt * 16 + lc) * 104 + ks * 32 + 4 * g + 16];
            bh8 bk = __builtin_shufflevector(blo, bhi, 0, 1, 2, 3, 4, 5, 6, 7);
            s16[nt] = __builtin_amdgcn_mfma_f32_16x16x32_bf16(aq, bk, s16[nt], 0, 0, 0);
        }
    }
    // ---- softmax over d (rows c = c0 + w*16 + g*4 + j, cols d = nt*16 + lc) ----
#pragma unroll
    for (int j = 0; j < 4; ++j) {
        float m = -1e30f;
#pragma unroll
        for (int nt = 0; nt < 16; ++nt) m = fmaxf(m, s16[nt][j]);
        m = fmaxf(m, __shfl_xor(m, 1));
        m = fmaxf(m, __shfl_xor(m, 2));
        m = fmaxf(m, __shfl_xor(m, 4));
        m = fmaxf(m, __shfl_xor(m, 8));
        float sum = 0.f;
#pragma unroll
        for (int nt = 0; nt < 16; ++nt) {
            float e = __expf(s16[nt][j] - m); s16[nt][j] = e; sum += e;
        }
        sum += __shfl_xor(sum, 1);
        sum += __shfl_xor(sum, 2);
        sum += __shfl_xor(sum, 4);
        sum += __shfl_xor(sum, 8);
        float inv = 1.f / sum;
#pragma unroll
        for (int nt = 0; nt < 16; ++nt)
            sP[(w * 16 + g * 4 + j) * 264 + nt * 16 + lc] = f2bf(s16[nt][j] * inv);
    }
    __syncthreads();

    // ---- PV: av[c][t] = sum_d P[c][d] V[d][t] ----
    f4 o6[6];
#pragma unroll
    for (int nt = 0; nt < 6; ++nt) o6[nt] = (f4){0.f, 0.f, 0.f, 0.f};
#pragma unroll
    for (int ks = 0; ks < 8; ++ks) {
        bh4 alo = *(const bh4*)&sP[(w * 16 + lc) * 264 + ks * 32 + 4 * g];
        bh4 ahi = *(const bh4*)&sP[(w * 16 + lc) * 264 + ks * 32 + 4 * g + 16];
        bh8 ap = __builtin_shufflevector(alo, ahi, 0, 1, 2, 3, 4, 5, 6, 7);
#pragma unroll
        for (int nt = 0; nt < 6; ++nt) {
            bh4 blo = *(const bh4*)&sV[(nt * 16 + lc) * 264 + ks * 32 + 4 * g];
            bh4 bhi = *(const bh4*)&sV[(nt * 16 + lc) * 264 + ks * 32 + 4 * g + 16];
            bh8 bv = __builtin_shufflevector(blo, bhi, 0, 1, 2, 3, 4, 5, 6, 7);
            o6[nt] = __builtin_amdgcn_mfma_f32_16x16x32_bf16(ap, bv, o6[nt], 0, 0, 0);
        }
    }
#pragma unroll
    for (int nt = 0; nt < 6; ++nt)
#pragma unroll
        for (int j = 0; j < 4; ++j) {
            int c = c0 + w * 16 + g * 4 + j;
            int t = nt * 16 + lc;
            avc[(((size_t)b * 256 + c) * 96 + v) * 96 + t] = f2bf(o6[nt][j]);
        }
}

// -------------------------------------------------------------------------
extern "C" void kernel_launch(void* const* d_in, const int* in_sizes, int n_in,
                              void* d_out, int out_size, void* d_ws, size_t ws_size,
                              hipStream_t stream)
{
    const float* x     = (const float*)d_in[0];
    const float* v_wq  = (const float*)d_in[1];
    const float* v_wk  = (const float*)d_in[2];
    const float* v_wv  = (const float*)d_in[3];
    const float* v_wo  = (const float*)d_in[4];
    const float* v_sig = (const float*)d_in[5];
    const float* t_wq  = (const float*)d_in[6];
    const float* t_wk  = (const float*)d_in[7];
    const float* t_wv  = (const float*)d_in[8];
    const float* t_wo  = (const float*)d_in[9];
    const float* t_sig = (const float*)d_in[10];
    const float* c_wq  = (const float*)d_in[11];
    const float* c_bq  = (const float*)d_in[12];
    const float* c_wk  = (const float*)d_in[13];
    const float* c_bk  = (const float*)d_in[14];
    const float* c_wv  = (const float*)d_in[15];
    const float* c_bv  = (const float*)d_in[16];
    const float* c_wo  = (const float*)d_in[17];
    const float* c_sig = (const float*)d_in[18];

    float*  out = (float*)d_out;
    ushort* ws  = (ushort*)d_ws;

    // ---- workspace layout (ushort units) ----
    const size_t XB   = 0;                       // x bf16 [8][256][96][96]
    const size_t QKV  = XB   + 18874368;         // fused proj out [8][192][96][96]
    const size_t QKVT = QKV  + 14155776;         // vt-transposed copy
    const size_t AVVT = QKVT + 14155776;         // av (v/t) [8][128][96][96]
    const size_t QC   = AVVT + 9437184;          // cAttn q [8][256][96][96]
    const size_t KCB  = QC   + 18874368;
    const size_t VCT  = KCB  + 18874368;         // cAttn v transposed [8][96][96][256]
    const size_t AVC  = VCT  + 18874368;         // cAttn av [8][256][96][96]
    const size_t PK   = AVC  + 18874368;         // packed weights
    // pack sub-offsets
    const size_t PK_PV  = PK;                    // proj v: 8*9*12*512 = 442368
    const size_t PK_PT  = PK_PV + 442368;
    const size_t PK_WOV = PK_PT + 442368;        // 4*9*16*512 = 294912
    const size_t PK_WOT = PK_WOV + 294912;
    const size_t PK_CQ  = PK_WOT + 294912;       // 8*1*16*512 = 65536
    const size_t PK_CK  = PK_CQ + 65536;
    const size_t PK_CV  = PK_CK + 65536;
    const size_t PK_CWO = PK_CV + 65536;         // 8*9*16*512 = 589824

    // out = x
    hipMemcpyAsync(out, x, (size_t)BB * CH * NVT * sizeof(float),
                   hipMemcpyDeviceToDevice, stream);

    // x -> bf16
    {
        int n = BB * CH * NVT;
        cvt_x_k<<<(n + 255) / 256, 256, 0, stream>>>(x, ws + XB, n);
    }

    // weight packs
    auto pack = [&](const float* w, size_t dst, int cin, int taps, int csrc,
                    int cobase, int cot) {
        int total = (cin >> 5) * taps * csrc * 32;
        wpack_k<<<(total + 255) / 256, 256, 0, stream>>>(w, ws + dst, cin, taps,
                                                          csrc, cobase, cot);
    };
    pack(v_wq, PK_PV, 256, 9, 32, 0, 12);
    pack(v_wk, PK_PV, 256, 9, 32, 32, 12);
    pack(v_wv, PK_PV, 256, 9, 128, 64, 12);
    pack(t_wq, PK_PT, 256, 9, 32, 0, 12);
    pack(t_wk, PK_PT, 256, 9, 32, 32, 12);
    pack(t_wv, PK_PT, 256, 9, 128, 64, 12);
    pack(v_wo, PK_WOV, 128, 9, 256, 0, 16);
    pack(t_wo, PK_WOT, 128, 9, 256, 0, 16);
    pack(c_wq, PK_CQ, 256, 1, 256, 0, 16);
    pack(c_wk, PK_CK, 256, 1, 256, 0, 16);
    pack(c_wv, PK_CV, 256, 1, 256, 0, 16);
    pack(c_wo, PK_CWO, 256, 9, 256, 0, 16);

    dim3 cgrid(96, BB);

    // ---- vAttn ----
    conv_mfma<9, 6, 0, false><<<cgrid, 256, 0, stream>>>(
        ws + XB, ws + PK_PV, ws + QKV, nullptr, nullptr, nullptr, 256);
    transpose_vt_k<<<BB * 192, 256, 0, stream>>>(ws + QKV, ws + QKVT);
    attn_vt_k<true><<<BB * 96, 256, 0, stream>>>(ws + QKVT, ws + AVVT);
    conv_mfma<9, 8, 3, false><<<cgrid, 256, 0, stream>>>(
        ws + AVVT, ws + PK_WOV, nullptr, out, nullptr, v_sig, 128);

    // ---- tAttn ----
    conv_mfma<9, 6, 0, false><<<cgrid, 256, 0, stream>>>(
        ws + XB, ws + PK_PT, ws + QKV, nullptr, nullptr, nullptr, 256);
    attn_vt_k<false><<<BB * 96, 256, 0, stream>>>(ws + QKV, ws + AVVT);
    conv_mfma<9, 8, 3, false><<<cgrid, 256, 0, stream>>>(
        ws + AVVT, ws + PK_WOT, nullptr, out, nullptr, t_sig, 128);

    // ---- cAttn ----
    conv_mfma<1, 8, 0, true><<<cgrid, 256, 0, stream>>>(
        ws + XB, ws + PK_CQ, ws + QC, nullptr, c_bq, nullptr, 256);
    conv_mfma<1, 8, 0, true><<<cgrid, 256, 0, stream>>>(
        ws + XB, ws + PK_CK, ws + KCB, nullptr, c_bk, nullptr, 256);
    conv_mfma<1, 8, 2, true><<<cgrid, 256, 0, stream>>>(
        ws + XB, ws + PK_CV, ws + VCT, nullptr, c_bv, nullptr, 256);
    attn_c_k<<<dim3(96, 4, BB), 256, 0, stream>>>(ws + QC, ws + KCB, ws + VCT,
                                                  ws + AVC);
    conv_mfma<9, 8, 3, false><<<cgrid, 256, 0, stream>>>(
        ws + AVC, ws + PK_CWO, nullptr, out, nullptr, c_sig, 256);
}

// Round 3
// 1161.977 us; speedup vs baseline: 50.3103x; 1.3497x over previous
//
#include <hip/hip_runtime.h>
#include <math.h>

#define BB  8
#define CH  256
#define NVT 9216        // 96*96

typedef short bh8 __attribute__((ext_vector_type(8)));
typedef short bh4 __attribute__((ext_vector_type(4)));
typedef float f4  __attribute__((ext_vector_type(4)));

__device__ __forceinline__ float bf2f(ushort u) {
    union { uint i; float f; } x; x.i = ((uint)u) << 16; return x.f;
}
__device__ __forceinline__ ushort f2bf(float f) {
    union { float f; uint i; } x; x.f = f;
    uint r = (x.i + 0x7FFFu + ((x.i >> 16) & 1u)) >> 16;
    return (ushort)r;
}

// -------------------------------------------------------------------------
// x fp32 -> bf16 compact
// -------------------------------------------------------------------------
__global__ __launch_bounds__(256) void cvt_x_k(const float* __restrict__ x,
                                               ushort* __restrict__ xb, int n)
{
    int i = blockIdx.x * 256 + threadIdx.x;
    if (i < n) xb[i] = f2bf(x[i]);
}

// -------------------------------------------------------------------------
// Pack conv weights [Csrc][CIN][TAPS] fp32 into MFMA A-fragment order bf16.
// dst short idx = (((kc*TAPS+tap)*COT + cot)*64 + lane)*8 + i
// k-granule: klocal = 16*(i>>2) + 4*(lane>>4) + (i&3), row = lane&15 = co&15
// -------------------------------------------------------------------------
__global__ __launch_bounds__(256) void wpack_k(const float* __restrict__ w,
    ushort* __restrict__ dst, int CIN, int TAPS, int Csrc, int coBase, int COT)
{
    int n = blockIdx.x * 256 + threadIdx.x;
    int total = (CIN >> 5) * TAPS * Csrc * 32;
    if (n >= total) return;
    int kl  = n & 31;
    int rem = n >> 5;
    int col = rem % Csrc; rem /= Csrc;
    int tap = rem % TAPS;
    int kc  = rem / TAPS;
    int ci  = kc * 32 + kl;
    int g   = (kl >> 2) & 3;
    int i   = ((kl >> 4) << 2) | (kl & 3);
    int cog = coBase + col;
    int cot = cog >> 4, lc = cog & 15;
    float v = w[((size_t)col * CIN + ci) * TAPS + tap];
    dst[((((size_t)kc * TAPS + tap) * COT + cot) * 64 + (g * 16 + lc)) * 8 + i] = f2bf(v);
}

// -------------------------------------------------------------------------
// Implicit-GEMM conv via MFMA 16x16x32 bf16.  512 threads = 8 waves.
// Block: (v0, b).  Wave: wc=w&3 co-quarter (CT tiles of 16), wt=w>>2 t-half.
// LDS x-tile: sx[vr][98 t'][40] with channel ci stored at permuted position
//   p' = perm(ci) ^ (((t'>>3)&3)<<3),  perm(ci)=8*((ci>>2)&3)+4*(ci>>4)+(ci&3)
// -> every lane's 8 k-elements are contiguous: ONE ds_read_b128 per B-frag,
//   16B-aligned (pitch 80B), bank-stride 20 -> 2-way (free). XOR spreads the
//   staging scatter-writes across banks.
// OMODE: 0 = bf16 compact [b][COUT][96][96]
//        2 = bf16 transposed [b][96][96][COUT]
//        3 = fp32 out[idx] += sig * conv
// -------------------------------------------------------------------------
template<int TAPS, int CT, int OMODE, bool HASBIAS>
__global__ __launch_bounds__(512) void conv_mfma(
    const ushort* __restrict__ xin, const ushort* __restrict__ wpk,
    ushort* __restrict__ obf, float* __restrict__ oacc,
    const float* __restrict__ bias, const float* __restrict__ sig, int CIN)
{
    constexpr int ROWS  = (TAPS == 9) ? 3 : 1;
    constexpr int PITCH = 40;           // shorts per t'-row (80 B, 16B-aligned)
    constexpr int TROW  = 98;           // t' = 0..97
    constexpr int COT   = CT * 4;
    constexpr int COUT  = COT * 16;
    __shared__ ushort sx[ROWS * TROW * PITCH];

    int v0 = blockIdx.x, b = blockIdx.y;
    int tid = threadIdx.x;
    int w = tid >> 6, l = tid & 63;
    int g = l >> 4, col = l & 15;
    int wc = w & 3, wt = w >> 2;

    f4 acc[CT][3];
#pragma unroll
    for (int ct = 0; ct < CT; ++ct)
#pragma unroll
        for (int nt = 0; nt < 3; ++nt) acc[ct][nt] = (f4){0.f, 0.f, 0.f, 0.f};

    const int KC = CIN >> 5;
    for (int kc = 0; kc < KC; ++kc) {
        if (kc) __syncthreads();
        // edge zero columns t'=0 and t'=97 (q=0 for both)
        for (int s = tid; s < 64 * ROWS; s += 512) {
            int e = s & 1, ci = (s >> 1) & 31, vr = s >> 6;
            int tp = e ? 97 : 0;
            int pb = (((ci >> 2) & 3) << 3) | ((ci >> 4) << 2) | (ci & 3);
            sx[(vr * TROW + tp) * PITCH + pb] = 0;
        }
        // main staging: bh8 global loads, 8 permuted u16 LDS writes each
        for (int s = tid; s < 32 * ROWS * 12; s += 512) {
            int m = s % 12, ci = (s / 12) & 31, vr = s / 384;
            int row = v0 + vr - ((TAPS == 9) ? 1 : 0);
            bh8 val = {0, 0, 0, 0, 0, 0, 0, 0};
            if (row >= 0 && row < 96)
                val = *(const bh8*)&xin[
                    (((size_t)b * CIN + kc * 32 + ci) * 96 + row) * 96 + 8 * m];
            int pb = (((ci >> 2) & 3) << 3) | ((ci >> 4) << 2) | (ci & 3);
            ushort* dst = &sx[(size_t)vr * TROW * PITCH];
#pragma unroll
            for (int u = 0; u < 8; ++u) {
                int tp = 8 * m + 1 + u;
                int pp = pb ^ (((tp >> 3) & 3) << 3);
                dst[tp * PITCH + pp] = (ushort)val[u];
            }
        }
        __syncthreads();
#pragma unroll
        for (int tap = 0; tap < TAPS; ++tap) {
            const int kh = (TAPS == 9) ? tap / 3 : 0;
            const int kw = (TAPS == 9) ? tap % 3 : 1;
            bh8 af[CT];
            const bh8* wp = (const bh8*)wpk;
#pragma unroll
            for (int ct = 0; ct < CT; ++ct)
                af[ct] = wp[(((size_t)kc * TAPS + tap) * COT + (wc * CT + ct)) * 64 + l];
#pragma unroll
            for (int nt = 0; nt < 3; ++nt) {
                int tp = wt * 48 + nt * 16 + col + kw;
                int q  = (tp >> 3) & 3;
                bh8 bf = *(const bh8*)&sx[(kh * TROW + tp) * PITCH + 8 * (g ^ q)];
#pragma unroll
                for (int ct = 0; ct < CT; ++ct)
                    acc[ct][nt] = __builtin_amdgcn_mfma_f32_16x16x32_bf16(
                        af[ct], bf, acc[ct][nt], 0, 0, 0);
            }
        }
    }

    // ---- epilogue ----
    float sg = 0.f;
    if (OMODE == 3) sg = sig[0];
#pragma unroll
    for (int ct = 0; ct < CT; ++ct) {
#pragma unroll
        for (int nt = 0; nt < 3; ++nt) {
            int tt = wt * 48 + nt * 16 + col;
            if (OMODE == 2) {
                bh4 o;
#pragma unroll
                for (int j = 0; j < 4; ++j) {
                    int cog = (wc * CT + ct) * 16 + g * 4 + j;
                    float val = acc[ct][nt][j];
                    if (HASBIAS) val += bias[cog];
                    o[j] = (short)f2bf(val);
                }
                int cb = (wc * CT + ct) * 16 + g * 4;
                *(bh4*)&obf[(((size_t)b * 96 + v0) * 96 + tt) * COUT + cb] = o;
            } else {
#pragma unroll
                for (int j = 0; j < 4; ++j) {
                    int cog = (wc * CT + ct) * 16 + g * 4 + j;
                    float val = acc[ct][nt][j];
                    if (HASBIAS) val += bias[cog];
                    size_t o = (((size_t)b * COUT + cog) * 96 + v0) * 96 + tt;
                    if (OMODE == 0) obf[o] = f2bf(val);
                    else            oacc[o] += sg * val;
                }
            }
        }
    }
}

// -------------------------------------------------------------------------
// transpose last two dims; input has channel-stride cs_in per b, cn channels
// -------------------------------------------------------------------------
__global__ __launch_bounds__(256) void transpose_vt_k(const ushort* __restrict__ in,
                                                      ushort* __restrict__ out,
                                                      int cs_in, int cn)
{
    __shared__ ushort tile[96][100];
    int b = blockIdx.x / cn, c = blockIdx.x % cn;
    size_t sbase = ((size_t)b * cs_in + c) * NVT;
    size_t dbase = (size_t)blockIdx.x * NVT;
    for (int n = threadIdx.x; n < NVT; n += 256) tile[n / 96][n % 96] = in[sbase + n];
    __syncthreads();
    for (int n = threadIdx.x; n < NVT; n += 256) out[dbase + n] = tile[n % 96][n / 96];
}

// -------------------------------------------------------------------------
// vAttn / tAttn core (fp32 VALU).  One block per (b,p).
// qkv element (ch, p, i) at ((b*cstride + cbase + ch)*96 + p)*96 + i
// q = ch 0..31, k = 32..63, v = 64..191.  av compact [b][128][96][96].
// -------------------------------------------------------------------------
template<bool OVER_V>
__global__ __launch_bounds__(256) void attn_vt_k(const ushort* __restrict__ qkv,
                                                 ushort* __restrict__ av,
                                                 int cstride, int cbase)
{
    __shared__ float sQ[96][36];
    __shared__ float sK[96][36];
    __shared__ float sV[32][96];
    __shared__ float sc[96][100];
    int b = blockIdx.x / 96, p = blockIdx.x % 96;
    int tid = threadIdx.x;
    const size_t base = ((size_t)b * cstride + cbase) * NVT + (size_t)p * 96;

    for (int n = tid; n < 3072; n += 256) {
        int c = n / 96, i = n % 96;
        sQ[i][c] = bf2f(qkv[base + (size_t)c * NVT + i]);
        sK[i][c] = bf2f(qkv[base + (size_t)(c + 32) * NVT + i]);
    }
    __syncthreads();

    for (int u = tid; u < 2304; u += 256) {
        int r = u / 24, w4 = (u % 24) * 4;
        float a0 = 0, a1 = 0, a2 = 0, a3 = 0;
#pragma unroll
        for (int c4 = 0; c4 < 8; ++c4) {
            f4 q  = *(const f4*)&sQ[r][c4 * 4];
            f4 k0 = *(const f4*)&sK[w4 + 0][c4 * 4];
            f4 k1 = *(const f4*)&sK[w4 + 1][c4 * 4];
            f4 k2 = *(const f4*)&sK[w4 + 2][c4 * 4];
            f4 k3 = *(const f4*)&sK[w4 + 3][c4 * 4];
            a0 = fmaf(q.x, k0.x, fmaf(q.y, k0.y, fmaf(q.z, k0.z, fmaf(q.w, k0.w, a0))));
            a1 = fmaf(q.x, k1.x, fmaf(q.y, k1.y, fmaf(q.z, k1.z, fmaf(q.w, k1.w, a1))));
            a2 = fmaf(q.x, k2.x, fmaf(q.y, k2.y, fmaf(q.z, k2.z, fmaf(q.w, k2.w, a2))));
            a3 = fmaf(q.x, k3.x, fmaf(q.y, k3.y, fmaf(q.z, k3.z, fmaf(q.w, k3.w, a3))));
        }
        f4 o = {a0, a1, a2, a3};
        *(f4*)&sc[r][w4] = o;
    }
    __syncthreads();

    if (tid < 96) {
        int r = tid;
        float m = -1e30f;
        for (int j = 0; j < 96; ++j) m = fmaxf(m, sc[r][j]);
        float ssum = 0.f;
        for (int j = 0; j < 96; ++j) { float e = __expf(sc[r][j] - m); sc[r][j] = e; ssum += e; }
        float inv = 1.f / ssum;
        for (int j = 0; j < 96; ++j) sc[r][j] *= inv;
    }
    __syncthreads();

    for (int ch = 0; ch < 4; ++ch) {
        if (ch) __syncthreads();
        for (int n = tid; n < 3072; n += 256) {
            int c = n / 96, i = n % 96;
            sV[c][i] = bf2f(qkv[base + (size_t)(64 + ch * 32 + c) * NVT + i]);
        }
        __syncthreads();
        for (int u = tid; u < 768; u += 256) {
            int c = u / 24, i0 = (u % 24) * 4;
            float a[4] = {0.f, 0.f, 0.f, 0.f};
            for (int w4 = 0; w4 < 24; ++w4) {
                f4 vv = *(const f4*)&sV[c][w4 * 4];
#pragma unroll
                for (int m = 0; m < 4; ++m) {
                    f4 s = *(const f4*)&sc[i0 + m][w4 * 4];
                    a[m] = fmaf(s.x, vv.x, fmaf(s.y, vv.y, fmaf(s.z, vv.z, fmaf(s.w, vv.w, a[m]))));
                }
            }
            int cg = ch * 32 + c;
#pragma unroll
            for (int m = 0; m < 4; ++m) {
                int i = i0 + m;
                size_t o = OVER_V ? (((size_t)b * 128 + cg) * 96 + i) * 96 + p
                                  : (((size_t)b * 128 + cg) * 96 + p) * 96 + i;
                av[o] = f2bf(a[m]);
            }
        }
    }
}

// -------------------------------------------------------------------------
// cAttn via MFMA: block per (v, cc, b); 64 c-rows, full 256 d, K over t=96.
// -------------------------------------------------------------------------
__global__ __launch_bounds__(256) void attn_c_k(const ushort* __restrict__ qc,
    const ushort* __restrict__ kc_, const ushort* __restrict__ vc,
    ushort* __restrict__ avc)
{
    __shared__ ushort sQ[64 * 104];
    __shared__ ushort sK[256 * 104];
    __shared__ ushort sV[96 * 264];
    __shared__ ushort sP[64 * 264];

    int v = blockIdx.x, cc = blockIdx.y, b = blockIdx.z;
    int c0 = cc * 64;
    int tid = threadIdx.x;
    int w = tid >> 6, l = tid & 63;
    int g = l >> 4, lc = l & 15;

    for (int s = tid; s < 64 * 12; s += 256) {
        int r = s / 12, sg = s % 12;
        *(bh8*)&sQ[r * 104 + sg * 8] =
            *(const bh8*)&qc[(((size_t)b * 256 + c0 + r) * 96 + v) * 96 + sg * 8];
    }
    for (int s = tid; s < 256 * 12; s += 256) {
        int r = s / 12, sg = s % 12;
        *(bh8*)&sK[r * 104 + sg * 8] =
            *(const bh8*)&kc_[(((size_t)b * 256 + r) * 96 + v) * 96 + sg * 8];
    }
    for (int s = tid; s < 96 * 32; s += 256) {
        int r = s / 32, sg = s % 32;
        *(bh8*)&sV[r * 264 + sg * 8] =
            *(const bh8*)&vc[(((size_t)b * 96 + v) * 96 + r) * 256 + sg * 8];
    }
    __syncthreads();

    f4 s16[16];
#pragma unroll
    for (int nt = 0; nt < 16; ++nt) s16[nt] = (f4){0.f, 0.f, 0.f, 0.f};
#pragma unroll
    for (int ks = 0; ks < 3; ++ks) {
        bh4 alo = *(const bh4*)&sQ[(w * 16 + lc) * 104 + ks * 32 + 4 * g];
        bh4 ahi = *(const bh4*)&sQ[(w * 16 + lc) * 104 + ks * 32 + 4 * g + 16];
        bh8 aq = __builtin_shufflevector(alo, ahi, 0, 1, 2, 3, 4, 5, 6, 7);
#pragma unroll
        for (int nt = 0; nt < 16; ++nt) {
            bh4 blo = *(const bh4*)&sK[(nt * 16 + lc) * 104 + ks * 32 + 4 * g];
            bh4 bhi = *(const bh4*)&sK[(nt * 16 + lc) * 104 + ks * 32 + 4 * g + 16];
            bh8 bk = __builtin_shufflevector(blo, bhi, 0, 1, 2, 3, 4, 5, 6, 7);
            s16[nt] = __builtin_amdgcn_mfma_f32_16x16x32_bf16(aq, bk, s16[nt], 0, 0, 0);
        }
    }
#pragma unroll
    for (int j = 0; j < 4; ++j) {
        float m = -1e30f;
#pragma unroll
        for (int nt = 0; nt < 16; ++nt) m = fmaxf(m, s16[nt][j]);
        m = fmaxf(m, __shfl_xor(m, 1));
        m = fmaxf(m, __shfl_xor(m, 2));
        m = fmaxf(m, __shfl_xor(m, 4));
        m = fmaxf(m, __shfl_xor(m, 8));
        float sum = 0.f;
#pragma unroll
        for (int nt = 0; nt < 16; ++nt) {
            float e = __expf(s16[nt][j] - m); s16[nt][j] = e; sum += e;
        }
        sum += __shfl_xor(sum, 1);
        sum += __shfl_xor(sum, 2);
        sum += __shfl_xor(sum, 4);
        sum += __shfl_xor(sum, 8);
        float inv = 1.f / sum;
#pragma unroll
        for (int nt = 0; nt < 16; ++nt)
            sP[(w * 16 + g * 4 + j) * 264 + nt * 16 + lc] = f2bf(s16[nt][j] * inv);
    }
    __syncthreads();

    f4 o6[6];
#pragma unroll
    for (int nt = 0; nt < 6; ++nt) o6[nt] = (f4){0.f, 0.f, 0.f, 0.f};
#pragma unroll
    for (int ks = 0; ks < 8; ++ks) {
        bh4 alo = *(const bh4*)&sP[(w * 16 + lc) * 264 + ks * 32 + 4 * g];
        bh4 ahi = *(const bh4*)&sP[(w * 16 + lc) * 264 + ks * 32 + 4 * g + 16];
        bh8 ap = __builtin_shufflevector(alo, ahi, 0, 1, 2, 3, 4, 5, 6, 7);
#pragma unroll
        for (int nt = 0; nt < 6; ++nt) {
            bh4 blo = *(const bh4*)&sV[(nt * 16 + lc) * 264 + ks * 32 + 4 * g];
            bh4 bhi = *(const bh4*)&sV[(nt * 16 + lc) * 264 + ks * 32 + 4 * g + 16];
            bh8 bv = __builtin_shufflevector(blo, bhi, 0, 1, 2, 3, 4, 5, 6, 7);
            o6[nt] = __builtin_amdgcn_mfma_f32_16x16x32_bf16(ap, bv, o6[nt], 0, 0, 0);
        }
    }
#pragma unroll
    for (int nt = 0; nt < 6; ++nt)
#pragma unroll
        for (int j = 0; j < 4; ++j) {
            int c = c0 + w * 16 + g * 4 + j;
            int t = nt * 16 + lc;
            avc[(((size_t)b * 256 + c) * 96 + v) * 96 + t] = f2bf(o6[nt][j]);
        }
}

// -------------------------------------------------------------------------
extern "C" void kernel_launch(void* const* d_in, const int* in_sizes, int n_in,
                              void* d_out, int out_size, void* d_ws, size_t ws_size,
                              hipStream_t stream)
{
    const float* x     = (const float*)d_in[0];
    const float* v_wq  = (const float*)d_in[1];
    const float* v_wk  = (const float*)d_in[2];
    const float* v_wv  = (const float*)d_in[3];
    const float* v_wo  = (const float*)d_in[4];
    const float* v_sig = (const float*)d_in[5];
    const float* t_wq  = (const float*)d_in[6];
    const float* t_wk  = (const float*)d_in[7];
    const float* t_wv  = (const float*)d_in[8];
    const float* t_wo  = (const float*)d_in[9];
    const float* t_sig = (const float*)d_in[10];
    const float* c_wq  = (const float*)d_in[11];
    const float* c_bq  = (const float*)d_in[12];
    const float* c_wk  = (const float*)d_in[13];
    const float* c_bk  = (const float*)d_in[14];
    const float* c_wv  = (const float*)d_in[15];
    const float* c_bv  = (const float*)d_in[16];
    const float* c_wo  = (const float*)d_in[17];
    const float* c_sig = (const float*)d_in[18];

    float*  out = (float*)d_out;
    ushort* ws  = (ushort*)d_ws;

    // ---- workspace layout (ushort units) ----
    const size_t XB   = 0;                       // x bf16 [8][256][9216]
    const size_t QKV  = XB   + 18874368;         // fused v+t proj [8][384][9216]
    const size_t QKVT = QKV  + 28311552;         // vt-transposed copy [8][192][9216]
    const size_t AVVT = QKVT + 14155776;         // av (v/t) [8][128][9216]
    const size_t QC   = AVVT + 9437184;          // cAttn q [8][256][9216]
    const size_t KCB  = QC   + 18874368;
    const size_t VCT  = KCB  + 18874368;         // cAttn v transposed [8][96][96][256]
    const size_t PK   = VCT  + 18874368;
    const size_t AVC  = QKVT;                    // alias: QKVT+AVVT dead by cAttn
    // pack sub-offsets
    const size_t PK_PVT = PK;                    // fused proj: 8*9*24*512 = 884736
    const size_t PK_WOV = PK_PVT + 884736;       // 4*9*16*512 = 294912
    const size_t PK_WOT = PK_WOV + 294912;
    const size_t PK_CQ  = PK_WOT + 294912;       // 8*1*16*512 = 65536
    const size_t PK_CK  = PK_CQ + 65536;
    const size_t PK_CV  = PK_CK + 65536;
    const size_t PK_CWO = PK_CV + 65536;         // 8*9*16*512 = 589824

    hipMemcpyAsync(out, x, (size_t)BB * CH * NVT * sizeof(float),
                   hipMemcpyDeviceToDevice, stream);

    {
        int n = BB * CH * NVT;
        cvt_x_k<<<(n + 255) / 256, 256, 0, stream>>>(x, ws + XB, n);
    }

    auto pack = [&](const float* w, size_t dst, int cin, int taps, int csrc,
                    int cobase, int cot) {
        int total = (cin >> 5) * taps * csrc * 32;
        wpack_k<<<(total + 255) / 256, 256, 0, stream>>>(w, ws + dst, cin, taps,
                                                          csrc, cobase, cot);
    };
    // fused v+t projection pack (COUT=384): v q/k/v at 0/32/64, t at 192/224/256
    pack(v_wq, PK_PVT, 256, 9, 32, 0, 24);
    pack(v_wk, PK_PVT, 256, 9, 32, 32, 24);
    pack(v_wv, PK_PVT, 256, 9, 128, 64, 24);
    pack(t_wq, PK_PVT, 256, 9, 32, 192, 24);
    pack(t_wk, PK_PVT, 256, 9, 32, 224, 24);
    pack(t_wv, PK_PVT, 256, 9, 128, 256, 24);
    pack(v_wo, PK_WOV, 128, 9, 256, 0, 16);
    pack(t_wo, PK_WOT, 128, 9, 256, 0, 16);
    pack(c_wq, PK_CQ, 256, 1, 256, 0, 16);
    pack(c_wk, PK_CK, 256, 1, 256, 0, 16);
    pack(c_wv, PK_CV, 256, 1, 256, 0, 16);
    pack(c_wo, PK_CWO, 256, 9, 256, 0, 16);

    dim3 cgrid(96, BB);

    // fused v+t qkv projection (COUT=384)
    conv_mfma<9, 6, 0, false><<<cgrid, 512, 0, stream>>>(
        ws + XB, ws + PK_PVT, ws + QKV, nullptr, nullptr, nullptr, 256);

    // ---- vAttn ----
    transpose_vt_k<<<BB * 192, 256, 0, stream>>>(ws + QKV, ws + QKVT, 384, 192);
    attn_vt_k<true><<<BB * 96, 256, 0, stream>>>(ws + QKVT, ws + AVVT, 192, 0);
    conv_mfma<9, 4, 3, false><<<cgrid, 512, 0, stream>>>(
        ws + AVVT, ws + PK_WOV, nullptr, out, nullptr, v_sig, 128);

    // ---- tAttn ----
    attn_vt_k<false><<<BB * 96, 256, 0, stream>>>(ws + QKV, ws + AVVT, 384, 192);
    conv_mfma<9, 4, 3, false><<<cgrid, 512, 0, stream>>>(
        ws + AVVT, ws + PK_WOT, nullptr, out, nullptr, t_sig, 128);

    // ---- cAttn ----
    conv_mfma<1, 4, 0, true><<<cgrid, 512, 0, stream>>>(
        ws + XB, ws + PK_CQ, ws + QC, nullptr, c_bq, nullptr, 256);
    conv_mfma<1, 4, 0, true><<<cgrid, 512, 0, stream>>>(
        ws + XB, ws + PK_CK, ws + KCB, nullptr, c_bk, nullptr, 256);
    conv_mfma<1, 4, 2, true><<<cgrid, 512, 0, stream>>>(
        ws + XB, ws + PK_CV, ws + VCT, nullptr, c_bv, nullptr, 256);
    attn_c_k<<<dim3(96, 4, BB), 256, 0, stream>>>(ws + QC, ws + KCB, ws + VCT,
                                                  ws + AVC);
    conv_mfma<9, 4, 3, false><<<cgrid, 512, 0, stream>>>(
        ws + AVC, ws + PK_CWO, nullptr, out, nullptr, c_sig, 256);
}

// Round 4
// 901.901 us; speedup vs baseline: 64.8181x; 1.2884x over previous
//
#include <hip/hip_runtime.h>
#include <math.h>

#define BB  8
#define CH  256
#define NVT 9216        // 96*96

typedef short bh8 __attribute__((ext_vector_type(8)));
typedef short bh4 __attribute__((ext_vector_type(4)));
typedef float f4  __attribute__((ext_vector_type(4)));

__device__ __forceinline__ float bf2f(ushort u) {
    union { uint i; float f; } x; x.i = ((uint)u) << 16; return x.f;
}
__device__ __forceinline__ ushort f2bf(float f) {
    union { float f; uint i; } x; x.f = f;
    uint r = (x.i + 0x7FFFu + ((x.i >> 16) & 1u)) >> 16;
    return (ushort)r;
}

// -------------------------------------------------------------------------
// x fp32 -> bf16 compact
// -------------------------------------------------------------------------
__global__ __launch_bounds__(256) void cvt_x_k(const float* __restrict__ x,
                                               ushort* __restrict__ xb, int n)
{
    int i = blockIdx.x * 256 + threadIdx.x;
    if (i < n) xb[i] = f2bf(x[i]);
}

// -------------------------------------------------------------------------
// Pack conv weights [Csrc][CIN][TAPS] fp32 into MFMA A-fragment order bf16.
// dst short idx = (((kc*TAPS+tap)*COT + cot)*64 + lane)*8 + i
// k-granule: klocal = 16*(i>>2) + 4*(lane>>4) + (i&3), row = lane&15 = co&15
// -------------------------------------------------------------------------
__global__ __launch_bounds__(256) void wpack_k(const float* __restrict__ w,
    ushort* __restrict__ dst, int CIN, int TAPS, int Csrc, int coBase, int COT)
{
    int n = blockIdx.x * 256 + threadIdx.x;
    int total = (CIN >> 5) * TAPS * Csrc * 32;
    if (n >= total) return;
    int kl  = n & 31;
    int rem = n >> 5;
    int col = rem % Csrc; rem /= Csrc;
    int tap = rem % TAPS;
    int kc  = rem / TAPS;
    int ci  = kc * 32 + kl;
    int g   = (kl >> 2) & 3;
    int i   = ((kl >> 4) << 2) | (kl & 3);
    int cog = coBase + col;
    int cot = cog >> 4, lc = cog & 15;
    float v = w[((size_t)col * CIN + ci) * TAPS + tap];
    dst[((((size_t)kc * TAPS + tap) * COT + cot) * 64 + (g * 16 + lc)) * 8 + i] = f2bf(v);
}

// -------------------------------------------------------------------------
// Implicit-GEMM conv via MFMA 16x16x32 bf16.  512 threads = 8 waves.
// LDS x-tile: sx[vr][98 t'][40], channel ci at permuted position
//   p' = perm(ci) ^ (((t'>>3)&3)<<3) -> ONE ds_read_b128 per B-frag.
// OMODE: 0 = bf16 compact, 2 = bf16 transposed, 3 = fp32 out += sig*conv
// -------------------------------------------------------------------------
template<int TAPS, int CT, int OMODE, bool HASBIAS>
__global__ __launch_bounds__(512) void conv_mfma(
    const ushort* __restrict__ xin, const ushort* __restrict__ wpk,
    ushort* __restrict__ obf, float* __restrict__ oacc,
    const float* __restrict__ bias, const float* __restrict__ sig, int CIN)
{
    constexpr int ROWS  = (TAPS == 9) ? 3 : 1;
    constexpr int PITCH = 40;
    constexpr int TROW  = 98;
    constexpr int COT   = CT * 4;
    constexpr int COUT  = COT * 16;
    __shared__ ushort sx[ROWS * TROW * PITCH];

    int v0 = blockIdx.x, b = blockIdx.y;
    int tid = threadIdx.x;
    int w = tid >> 6, l = tid & 63;
    int g = l >> 4, col = l & 15;
    int wc = w & 3, wt = w >> 2;

    f4 acc[CT][3];
#pragma unroll
    for (int ct = 0; ct < CT; ++ct)
#pragma unroll
        for (int nt = 0; nt < 3; ++nt) acc[ct][nt] = (f4){0.f, 0.f, 0.f, 0.f};

    const int KC = CIN >> 5;
    for (int kc = 0; kc < KC; ++kc) {
        if (kc) __syncthreads();
        for (int s = tid; s < 64 * ROWS; s += 512) {
            int e = s & 1, ci = (s >> 1) & 31, vr = s >> 6;
            int tp = e ? 97 : 0;
            int pb = (((ci >> 2) & 3) << 3) | ((ci >> 4) << 2) | (ci & 3);
            sx[(vr * TROW + tp) * PITCH + pb] = 0;
        }
        for (int s = tid; s < 32 * ROWS * 12; s += 512) {
            int m = s % 12, ci = (s / 12) & 31, vr = s / 384;
            int row = v0 + vr - ((TAPS == 9) ? 1 : 0);
            bh8 val = {0, 0, 0, 0, 0, 0, 0, 0};
            if (row >= 0 && row < 96)
                val = *(const bh8*)&xin[
                    (((size_t)b * CIN + kc * 32 + ci) * 96 + row) * 96 + 8 * m];
            int pb = (((ci >> 2) & 3) << 3) | ((ci >> 4) << 2) | (ci & 3);
            ushort* dst = &sx[(size_t)vr * TROW * PITCH];
#pragma unroll
            for (int u = 0; u < 8; ++u) {
                int tp = 8 * m + 1 + u;
                int pp = pb ^ (((tp >> 3) & 3) << 3);
                dst[tp * PITCH + pp] = (ushort)val[u];
            }
        }
        __syncthreads();
#pragma unroll
        for (int tap = 0; tap < TAPS; ++tap) {
            const int kh = (TAPS == 9) ? tap / 3 : 0;
            const int kw = (TAPS == 9) ? tap % 3 : 1;
            bh8 af[CT];
            const bh8* wp = (const bh8*)wpk;
#pragma unroll
            for (int ct = 0; ct < CT; ++ct)
                af[ct] = wp[(((size_t)kc * TAPS + tap) * COT + (wc * CT + ct)) * 64 + l];
#pragma unroll
            for (int nt = 0; nt < 3; ++nt) {
                int tp = wt * 48 + nt * 16 + col + kw;
                int q  = (tp >> 3) & 3;
                bh8 bf = *(const bh8*)&sx[(kh * TROW + tp) * PITCH + 8 * (g ^ q)];
#pragma unroll
                for (int ct = 0; ct < CT; ++ct)
                    acc[ct][nt] = __builtin_amdgcn_mfma_f32_16x16x32_bf16(
                        af[ct], bf, acc[ct][nt], 0, 0, 0);
            }
        }
    }

    float sg = 0.f;
    if (OMODE == 3) sg = sig[0];
#pragma unroll
    for (int ct = 0; ct < CT; ++ct) {
#pragma unroll
        for (int nt = 0; nt < 3; ++nt) {
            int tt = wt * 48 + nt * 16 + col;
            if (OMODE == 2) {
                bh4 o;
#pragma unroll
                for (int j = 0; j < 4; ++j) {
                    int cog = (wc * CT + ct) * 16 + g * 4 + j;
                    float val = acc[ct][nt][j];
                    if (HASBIAS) val += bias[cog];
                    o[j] = (short)f2bf(val);
                }
                int cb = (wc * CT + ct) * 16 + g * 4;
                *(bh4*)&obf[(((size_t)b * 96 + v0) * 96 + tt) * COUT + cb] = o;
            } else {
#pragma unroll
                for (int j = 0; j < 4; ++j) {
                    int cog = (wc * CT + ct) * 16 + g * 4 + j;
                    float val = acc[ct][nt][j];
                    if (HASBIAS) val += bias[cog];
                    size_t o = (((size_t)b * COUT + cog) * 96 + v0) * 96 + tt;
                    if (OMODE == 0) obf[o] = f2bf(val);
                    else            oacc[o] += sg * val;
                }
            }
        }
    }
}

// -------------------------------------------------------------------------
// transpose last two dims; input has channel-stride cs_in per b, cn channels
// -------------------------------------------------------------------------
__global__ __launch_bounds__(256) void transpose_vt_k(const ushort* __restrict__ in,
                                                      ushort* __restrict__ out,
                                                      int cs_in, int cn)
{
    __shared__ ushort tile[96][100];
    int b = blockIdx.x / cn, c = blockIdx.x % cn;
    size_t sbase = ((size_t)b * cs_in + c) * NVT;
    size_t dbase = (size_t)blockIdx.x * NVT;
    for (int n = threadIdx.x; n < NVT; n += 256) tile[n / 96][n % 96] = in[sbase + n];
    __syncthreads();
    for (int n = threadIdx.x; n < NVT; n += 256) out[dbase + n] = tile[n % 96][n / 96];
}

// -------------------------------------------------------------------------
// vAttn / tAttn via MFMA with swapped operands.  384 thr = 6 waves; one (b,p)
// slice per block; wave wv owns r-tile nt=wv (16 q-rows).
//   S^T[w,r] = mfma(A=K^T, B=Q^T)  ->  lane holds P^T[16mt+4g+j][r=lc]
//   softmax over w: 24 in-lane + shfl_xor(16,32)
//   post-softmax registers ARE the PV B-fragment (w = 32ks+16(i>>2)+4g+(i&3))
//   av^T[c,r] = mfma(A=V[c][w] from LDS, B=P^T in-reg).  No P LDS roundtrip.
// qkv element (ch,p,i) at ((b*cstride+cbase+ch)*96+p)*96+i; q ch 0..31,
// k 32..63, v 64..191.  av written compact [b][128][96][96].
// -------------------------------------------------------------------------
template<bool OVER_V>
__global__ __launch_bounds__(384) void attn_vt_mfma_k(const ushort* __restrict__ qkv,
                                                      ushort* __restrict__ av,
                                                      int cstride, int cbase)
{
    __shared__ ushort sQT[96 * 40];   // [i][c] transposed
    __shared__ ushort sKT[96 * 40];
    __shared__ ushort sV[128 * 104];  // [c][i] direct

    int b = blockIdx.x / 96, p = blockIdx.x % 96;
    int tid = threadIdx.x;
    int wv = tid >> 6, l = tid & 63;
    int g = l >> 4, lc = l & 15;

    const size_t base = ((size_t)b * cstride + cbase) * (size_t)NVT + (size_t)p * 96;

    // Q,K transposed into LDS (scatter u16 writes)
    for (int s = tid; s < 768; s += 384) {
        int hf = s / 384;             // 0 = Q, 1 = K
        int c  = (s % 384) / 12;
        int m  = s % 12;
        bh8 val = *(const bh8*)&qkv[base + (size_t)(hf * 32 + c) * NVT + 8 * m];
        ushort* dst = hf ? sKT : sQT;
#pragma unroll
        for (int u = 0; u < 8; ++u)
            dst[(8 * m + u) * 40 + c] = (ushort)val[u];
    }
    // V direct rows
    for (int s = tid; s < 1536; s += 384) {
        int c = s / 12, m = s % 12;
        *(bh8*)&sV[c * 104 + 8 * m] =
            *(const bh8*)&qkv[base + (size_t)(64 + c) * NVT + 8 * m];
    }
    __syncthreads();

    // ---- S^T = K^T . Q^T  (K = 32 channels, one MFMA k-step) ----
    bh4 qlo = *(const bh4*)&sQT[(wv * 16 + lc) * 40 + 4 * g];
    bh4 qhi = *(const bh4*)&sQT[(wv * 16 + lc) * 40 + 4 * g + 16];
    bh8 bq = __builtin_shufflevector(qlo, qhi, 0, 1, 2, 3, 4, 5, 6, 7);

    f4 st[6];
#pragma unroll
    for (int mt = 0; mt < 6; ++mt) {
        bh4 alo = *(const bh4*)&sKT[(mt * 16 + lc) * 40 + 4 * g];
        bh4 ahi = *(const bh4*)&sKT[(mt * 16 + lc) * 40 + 4 * g + 16];
        bh8 ak = __builtin_shufflevector(alo, ahi, 0, 1, 2, 3, 4, 5, 6, 7);
        st[mt] = __builtin_amdgcn_mfma_f32_16x16x32_bf16(ak, bq,
                                                         (f4){0.f, 0.f, 0.f, 0.f},
                                                         0, 0, 0);
    }

    // ---- softmax over w (rows of S^T): in-lane 24 + cross-g shfl ----
    float mx = -1e30f;
#pragma unroll
    for (int mt = 0; mt < 6; ++mt)
#pragma unroll
        for (int j = 0; j < 4; ++j) mx = fmaxf(mx, st[mt][j]);
    mx = fmaxf(mx, __shfl_xor(mx, 16));
    mx = fmaxf(mx, __shfl_xor(mx, 32));
    float sum = 0.f;
#pragma unroll
    for (int mt = 0; mt < 6; ++mt)
#pragma unroll
        for (int j = 0; j < 4; ++j) {
            float e = __expf(st[mt][j] - mx);
            st[mt][j] = e;
            sum += e;
        }
    sum += __shfl_xor(sum, 16);
    sum += __shfl_xor(sum, 32);
    float inv = 1.f / sum;

    // ---- P^T bf16 B-fragments (pure in-register repack) ----
    bh8 pf[3];
#pragma unroll
    for (int ks = 0; ks < 3; ++ks) {
        bh8 t;
#pragma unroll
        for (int i = 0; i < 8; ++i)
            t[i] = (short)f2bf(st[2 * ks + (i >> 2)][i & 3] * inv);
        pf[ks] = t;
    }

    // ---- av^T = V . P^T ----
    f4 acc[8];
#pragma unroll
    for (int mt = 0; mt < 8; ++mt) acc[mt] = (f4){0.f, 0.f, 0.f, 0.f};
#pragma unroll
    for (int ks = 0; ks < 3; ++ks)
#pragma unroll
        for (int mt = 0; mt < 8; ++mt) {
            bh4 alo = *(const bh4*)&sV[(mt * 16 + lc) * 104 + ks * 32 + 4 * g];
            bh4 ahi = *(const bh4*)&sV[(mt * 16 + lc) * 104 + ks * 32 + 4 * g + 16];
            bh8 avf = __builtin_shufflevector(alo, ahi, 0, 1, 2, 3, 4, 5, 6, 7);
            acc[mt] = __builtin_amdgcn_mfma_f32_16x16x32_bf16(avf, pf[ks],
                                                              acc[mt], 0, 0, 0);
        }

    // ---- write av (c = 16mt+4g+j, i = wv*16+lc) ----
    int i = wv * 16 + lc;
#pragma unroll
    for (int mt = 0; mt < 8; ++mt)
#pragma unroll
        for (int j = 0; j < 4; ++j) {
            int c = mt * 16 + g * 4 + j;
            size_t o = OVER_V ? ((((size_t)b * 128 + c) * 96 + i) * 96 + p)
                              : ((((size_t)b * 128 + c) * 96 + p) * 96 + i);
            av[o] = f2bf(acc[mt][j]);
        }
}

// -------------------------------------------------------------------------
// cAttn via MFMA: block per (v, cc, b); 64 c-rows, full 256 d, K over t=96.
// -------------------------------------------------------------------------
__global__ __launch_bounds__(256) void attn_c_k(const ushort* __restrict__ qc,
    const ushort* __restrict__ kc_, const ushort* __restrict__ vc,
    ushort* __restrict__ avc)
{
    __shared__ ushort sQ[64 * 104];
    __shared__ ushort sK[256 * 104];
    __shared__ ushort sV[96 * 264];
    __shared__ ushort sP[64 * 264];

    int v = blockIdx.x, cc = blockIdx.y, b = blockIdx.z;
    int c0 = cc * 64;
    int tid = threadIdx.x;
    int w = tid >> 6, l = tid & 63;
    int g = l >> 4, lc = l & 15;

    for (int s = tid; s < 64 * 12; s += 256) {
        int r = s / 12, sg = s % 12;
        *(bh8*)&sQ[r * 104 + sg * 8] =
            *(const bh8*)&qc[(((size_t)b * 256 + c0 + r) * 96 + v) * 96 + sg * 8];
    }
    for (int s = tid; s < 256 * 12; s += 256) {
        int r = s / 12, sg = s % 12;
        *(bh8*)&sK[r * 104 + sg * 8] =
            *(const bh8*)&kc_[(((size_t)b * 256 + r) * 96 + v) * 96 + sg * 8];
    }
    for (int s = tid; s < 96 * 32; s += 256) {
        int r = s / 32, sg = s % 32;
        *(bh8*)&sV[r * 264 + sg * 8] =
            *(const bh8*)&vc[(((size_t)b * 96 + v) * 96 + r) * 256 + sg * 8];
    }
    __syncthreads();

    f4 s16[16];
#pragma unroll
    for (int nt = 0; nt < 16; ++nt) s16[nt] = (f4){0.f, 0.f, 0.f, 0.f};
#pragma unroll
    for (int ks = 0; ks < 3; ++ks) {
        bh4 alo = *(const bh4*)&sQ[(w * 16 + lc) * 104 + ks * 32 + 4 * g];
        bh4 ahi = *(const bh4*)&sQ[(w * 16 + lc) * 104 + ks * 32 + 4 * g + 16];
        bh8 aq = __builtin_shufflevector(alo, ahi, 0, 1, 2, 3, 4, 5, 6, 7);
#pragma unroll
        for (int nt = 0; nt < 16; ++nt) {
            bh4 blo = *(const bh4*)&sK[(nt * 16 + lc) * 104 + ks * 32 + 4 * g];
            bh4 bhi = *(const bh4*)&sK[(nt * 16 + lc) * 104 + ks * 32 + 4 * g + 16];
            bh8 bk = __builtin_shufflevector(blo, bhi, 0, 1, 2, 3, 4, 5, 6, 7);
            s16[nt] = __builtin_amdgcn_mfma_f32_16x16x32_bf16(aq, bk, s16[nt], 0, 0, 0);
        }
    }
#pragma unroll
    for (int j = 0; j < 4; ++j) {
        float m = -1e30f;
#pragma unroll
        for (int nt = 0; nt < 16; ++nt) m = fmaxf(m, s16[nt][j]);
        m = fmaxf(m, __shfl_xor(m, 1));
        m = fmaxf(m, __shfl_xor(m, 2));
        m = fmaxf(m, __shfl_xor(m, 4));
        m = fmaxf(m, __shfl_xor(m, 8));
        float sum = 0.f;
#pragma unroll
        for (int nt = 0; nt < 16; ++nt) {
            float e = __expf(s16[nt][j] - m); s16[nt][j] = e; sum += e;
        }
        sum += __shfl_xor(sum, 1);
        sum += __shfl_xor(sum, 2);
        sum += __shfl_xor(sum, 4);
        sum += __shfl_xor(sum, 8);
        float inv = 1.f / sum;
#pragma unroll
        for (int nt = 0; nt < 16; ++nt)
            sP[(w * 16 + g * 4 + j) * 264 + nt * 16 + lc] = f2bf(s16[nt][j] * inv);
    }
    __syncthreads();

    f4 o6[6];
#pragma unroll
    for (int nt = 0; nt < 6; ++nt) o6[nt] = (f4){0.f, 0.f, 0.f, 0.f};
#pragma unroll
    for (int ks = 0; ks < 8; ++ks) {
        bh4 alo = *(const bh4*)&sP[(w * 16 + lc) * 264 + ks * 32 + 4 * g];
        bh4 ahi = *(const bh4*)&sP[(w * 16 + lc) * 264 + ks * 32 + 4 * g + 16];
        bh8 ap = __builtin_shufflevector(alo, ahi, 0, 1, 2, 3, 4, 5, 6, 7);
#pragma unroll
        for (int nt = 0; nt < 6; ++nt) {
            bh4 blo = *(const bh4*)&sV[(nt * 16 + lc) * 264 + ks * 32 + 4 * g];
            bh4 bhi = *(const bh4*)&sV[(nt * 16 + lc) * 264 + ks * 32 + 4 * g + 16];
            bh8 bv = __builtin_shufflevector(blo, bhi, 0, 1, 2, 3, 4, 5, 6, 7);
            o6[nt] = __builtin_amdgcn_mfma_f32_16x16x32_bf16(ap, bv, o6[nt], 0, 0, 0);
        }
    }
#pragma unroll
    for (int nt = 0; nt < 6; ++nt)
#pragma unroll
        for (int j = 0; j < 4; ++j) {
            int c = c0 + w * 16 + g * 4 + j;
            int t = nt * 16 + lc;
            avc[(((size_t)b * 256 + c) * 96 + v) * 96 + t] = f2bf(o6[nt][j]);
        }
}

// -------------------------------------------------------------------------
extern "C" void kernel_launch(void* const* d_in, const int* in_sizes, int n_in,
                              void* d_out, int out_size, void* d_ws, size_t ws_size,
                              hipStream_t stream)
{
    const float* x     = (const float*)d_in[0];
    const float* v_wq  = (const float*)d_in[1];
    const float* v_wk  = (const float*)d_in[2];
    const float* v_wv  = (const float*)d_in[3];
    const float* v_wo  = (const float*)d_in[4];
    const float* v_sig = (const float*)d_in[5];
    const float* t_wq  = (const float*)d_in[6];
    const float* t_wk  = (const float*)d_in[7];
    const float* t_wv  = (const float*)d_in[8];
    const float* t_wo  = (const float*)d_in[9];
    const float* t_sig = (const float*)d_in[10];
    const float* c_wq  = (const float*)d_in[11];
    const float* c_bq  = (const float*)d_in[12];
    const float* c_wk  = (const float*)d_in[13];
    const float* c_bk  = (const float*)d_in[14];
    const float* c_wv  = (const float*)d_in[15];
    const float* c_bv  = (const float*)d_in[16];
    const float* c_wo  = (const float*)d_in[17];
    const float* c_sig = (const float*)d_in[18];

    float*  out = (float*)d_out;
    ushort* ws  = (ushort*)d_ws;

    // ---- workspace layout (ushort units) ----
    const size_t XB   = 0;                       // x bf16 [8][256][9216]
    const size_t QKV  = XB   + 18874368;         // fused v+t proj [8][384][9216]
    const size_t QKVT = QKV  + 28311552;         // vt-transposed copy [8][192][9216]
    const size_t AVVT = QKVT + 14155776;         // av (v/t) [8][128][9216]
    const size_t QC   = AVVT + 9437184;          // cAttn q [8][256][9216]
    const size_t KCB  = QC   + 18874368;
    const size_t VCT  = KCB  + 18874368;         // cAttn v transposed
    const size_t PK   = VCT  + 18874368;
    const size_t AVC  = QKVT;                    // alias: QKVT+AVVT dead by cAttn
    const size_t PK_PVT = PK;                    // fused proj: 884736
    const size_t PK_WOV = PK_PVT + 884736;
    const size_t PK_WOT = PK_WOV + 294912;
    const size_t PK_CQ  = PK_WOT + 294912;
    const size_t PK_CK  = PK_CQ + 65536;
    const size_t PK_CV  = PK_CK + 65536;
    const size_t PK_CWO = PK_CV + 65536;

    hipMemcpyAsync(out, x, (size_t)BB * CH * NVT * sizeof(float),
                   hipMemcpyDeviceToDevice, stream);

    {
        int n = BB * CH * NVT;
        cvt_x_k<<<(n + 255) / 256, 256, 0, stream>>>(x, ws + XB, n);
    }

    auto pack = [&](const float* w, size_t dst, int cin, int taps, int csrc,
                    int cobase, int cot) {
        int total = (cin >> 5) * taps * csrc * 32;
        wpack_k<<<(total + 255) / 256, 256, 0, stream>>>(w, ws + dst, cin, taps,
                                                          csrc, cobase, cot);
    };
    pack(v_wq, PK_PVT, 256, 9, 32, 0, 24);
    pack(v_wk, PK_PVT, 256, 9, 32, 32, 24);
    pack(v_wv, PK_PVT, 256, 9, 128, 64, 24);
    pack(t_wq, PK_PVT, 256, 9, 32, 192, 24);
    pack(t_wk, PK_PVT, 256, 9, 32, 224, 24);
    pack(t_wv, PK_PVT, 256, 9, 128, 256, 24);
    pack(v_wo, PK_WOV, 128, 9, 256, 0, 16);
    pack(t_wo, PK_WOT, 128, 9, 256, 0, 16);
    pack(c_wq, PK_CQ, 256, 1, 256, 0, 16);
    pack(c_wk, PK_CK, 256, 1, 256, 0, 16);
    pack(c_wv, PK_CV, 256, 1, 256, 0, 16);
    pack(c_wo, PK_CWO, 256, 9, 256, 0, 16);

    dim3 cgrid(96, BB);

    // fused v+t qkv projection (COUT=384)
    conv_mfma<9, 6, 0, false><<<cgrid, 512, 0, stream>>>(
        ws + XB, ws + PK_PVT, ws + QKV, nullptr, nullptr, nullptr, 256);

    // ---- vAttn ----
    transpose_vt_k<<<BB * 192, 256, 0, stream>>>(ws + QKV, ws + QKVT, 384, 192);
    attn_vt_mfma_k<true><<<BB * 96, 384, 0, stream>>>(ws + QKVT, ws + AVVT, 192, 0);
    conv_mfma<9, 4, 3, false><<<cgrid, 512, 0, stream>>>(
        ws + AVVT, ws + PK_WOV, nullptr, out, nullptr, v_sig, 128);

    // ---- tAttn ----
    attn_vt_mfma_k<false><<<BB * 96, 384, 0, stream>>>(ws + QKV, ws + AVVT, 384, 192);
    conv_mfma<9, 4, 3, false><<<cgrid, 512, 0, stream>>>(
        ws + AVVT, ws + PK_WOT, nullptr, out, nullptr, t_sig, 128);

    // ---- cAttn ----
    conv_mfma<1, 4, 0, true><<<cgrid, 512, 0, stream>>>(
        ws + XB, ws + PK_CQ, ws + QC, nullptr, c_bq, nullptr, 256);
    conv_mfma<1, 4, 0, true><<<cgrid, 512, 0, stream>>>(
        ws + XB, ws + PK_CK, ws + KCB, nullptr, c_bk, nullptr, 256);
    conv_mfma<1, 4, 2, true><<<cgrid, 512, 0, stream>>>(
        ws + XB, ws + PK_CV, ws + VCT, nullptr, c_bv, nullptr, 256);
    attn_c_k<<<dim3(96, 4, BB), 256, 0, stream>>>(ws + QC, ws + KCB, ws + VCT,
                                                  ws + AVC);
    conv_mfma<9, 4, 3, false><<<cgrid, 512, 0, stream>>>(
        ws + AVC, ws + PK_CWO, nullptr, out, nullptr, c_sig, 256);
}

// Round 5
// 716.914 us; speedup vs baseline: 81.5433x; 1.2580x over previous
//
#include <hip/hip_runtime.h>
#include <math.h>

#define BB  8
#define CH  256
#define NVT 9216        // 96*96
#define PLN (98*98*32)  // padded NC32 plane: 307328 shorts
#define PROW (98*32)    // padded row: 3136 shorts

typedef short bh8 __attribute__((ext_vector_type(8)));
typedef short bh4 __attribute__((ext_vector_type(4)));
typedef float f4  __attribute__((ext_vector_type(4)));

__device__ __forceinline__ float bf2f(ushort u) {
    union { uint i; float f; } x; x.i = ((uint)u) << 16; return x.f;
}
__device__ __forceinline__ ushort f2bf(float f) {
    union { float f; uint i; } x; x.f = f;
    uint r = (x.i + 0x7FFFu + ((x.i >> 16) & 1u)) >> 16;
    return (ushort)r;
}
// channel permutation within a 32-block: position of ci such that 8 contiguous
// shorts at 8*g are exactly the MFMA k-granule ci = 16*(i>>2)+4*g+(i&3)
__device__ __forceinline__ int cperm(int ci) {
    return 8 * ((ci >> 2) & 3) + 4 * (ci >> 4) + (ci & 3);
}
__device__ __forceinline__ void gld16(const void* g, void* l) {
    __builtin_amdgcn_global_load_lds(
        (const __attribute__((address_space(1))) void*)g,
        (__attribute__((address_space(3))) void*)l, 16, 0, 0);
}

// -------------------------------------------------------------------------
// zero the pad borders of the NC32 padded buffers (x32: 64 planes, avall: 128)
// -------------------------------------------------------------------------
__global__ __launch_bounds__(256) void pad_zero_k(ushort* __restrict__ x32,
                                                  ushort* __restrict__ avall)
{
    int p = blockIdx.x;
    ushort* base = (p < 64) ? x32 + (size_t)p * PLN
                            : avall + (size_t)(p - 64) * PLN;
    const bh8 z = {0,0,0,0,0,0,0,0};
    // n < 392: row v'=0 ; n < 784: row v'=97 ; else cols t'=0/97 for v'=1..96
    for (int n = threadIdx.x; n < 1552; n += 256) {
        size_t off;
        if (n < 392)       off = (size_t)n * 8;
        else if (n < 784)  off = (size_t)97 * PROW + (size_t)(n - 392) * 8;
        else {
            int m = n - 784;               // 768 entries: 96 v' x 2 sides x 4
            int vq = m >> 3, side = (m >> 2) & 1, sub = m & 3;
            off = ((size_t)(vq + 1) * 98 + side * 97) * 32 + sub * 8;
        }
        *(bh8*)&base[off] = z;
    }
}

// -------------------------------------------------------------------------
// x NCHW fp32 -> NC32HW32 padded perm'd bf16
// -------------------------------------------------------------------------
__global__ __launch_bounds__(256) void cvt_x32_k(const float* __restrict__ x,
                                                 ushort* __restrict__ x32)
{
    __shared__ ushort tile[96 * 32];   // [t][perm ci]
    int v = blockIdx.x, kc = blockIdx.y, b = blockIdx.z;
    int ci = threadIdx.x >> 3, tp = threadIdx.x & 7;
    const float* src = x + (((size_t)(b * 256 + kc * 32 + ci)) * 96 + v) * 96 + tp * 12;
    int pc = cperm(ci);
#pragma unroll
    for (int u = 0; u < 12; ++u)
        tile[(tp * 12 + u) * 32 + pc] = f2bf(src[u]);
    __syncthreads();
    ushort* dst = x32 + (((size_t)(b * 8 + kc) * 98 + v + 1) * 98 + 1) * 32;
    for (int n = threadIdx.x; n < 384; n += 256)
        *(bh8*)&dst[n * 8] = *(const bh8*)&tile[n * 8];
}

// -------------------------------------------------------------------------
// Pack conv weights [Csrc][CIN][TAPS] fp32 -> MFMA A-frag order bf16,
// optionally scaled; kcBase offsets the K-section (for CIN-concat fusion).
// -------------------------------------------------------------------------
__global__ __launch_bounds__(256) void wpack_k(const float* __restrict__ w,
    ushort* __restrict__ dst, int CIN, int TAPS, int Csrc, int coBase, int COT,
    int kcBase, const float* __restrict__ scale)
{
    int n = blockIdx.x * 256 + threadIdx.x;
    int total = (CIN >> 5) * TAPS * Csrc * 32;
    if (n >= total) return;
    int kl  = n & 31;
    int rem = n >> 5;
    int col = rem % Csrc; rem /= Csrc;
    int tap = rem % TAPS;
    int kc  = rem / TAPS;
    int ci  = kc * 32 + kl;
    int g   = (kl >> 2) & 3;
    int i   = ((kl >> 4) << 2) | (kl & 3);
    int cog = coBase + col;
    int cot = cog >> 4, lc = cog & 15;
    float v = w[((size_t)col * CIN + ci) * TAPS + tap];
    if (scale) v *= scale[0];
    dst[((((size_t)(kcBase + kc) * TAPS + tap) * COT + cot) * 64 + (g * 16 + lc)) * 8 + i]
        = f2bf(v);
}

// -------------------------------------------------------------------------
// Implicit-GEMM conv, NC32 padded input, DMA-staged, 2-phase pipelined.
// 512 thr = 8 waves; wave (wc=w&3 co-quarter, wt=w>>2 t-half).
// OMODE: 0 = bf16 NCHW-compact planes; 2 = bf16 [b][96][96][COUT];
//        5 = fp32 out = xres + acc
// -------------------------------------------------------------------------
template<int TAPS, int CT, int OMODE>
__global__ __launch_bounds__(512, 4) void conv_mfma(
    const ushort* __restrict__ xin, const ushort* __restrict__ wpk,
    ushort* __restrict__ obf, const float* __restrict__ xres,
    float* __restrict__ oacc, const float* __restrict__ bias, int KC)
{
    constexpr int ROWS   = (TAPS == 9) ? 3 : 1;
    constexpr int SLABS  = ROWS * PROW;                 // shorts
    constexpr int CHUNKS = (SLABS * 2 + 1023) / 1024;   // 19 or 7
    constexpr int BUFSZ  = CHUNKS * 512;                // shorts
    constexpr int COT    = CT * 4;
    constexpr int COUT   = COT * 16;
    __shared__ ushort sx[2][BUFSZ];

    const int v0 = blockIdx.x, b = blockIdx.y;
    const int tid = threadIdx.x;
    const int w = tid >> 6, l = tid & 63;
    const int g = l >> 4, lc = l & 15;
    const int wc = w & 3, wt = w >> 2;

    f4 acc[CT][3];
#pragma unroll
    for (int ct = 0; ct < CT; ++ct)
#pragma unroll
        for (int nt = 0; nt < 3; ++nt) acc[ct][nt] = (f4){0.f, 0.f, 0.f, 0.f};

    auto stage = [&](int kc, int buf) {
        const ushort* src = xin +
            (((size_t)b * KC + kc) * 98 + v0 + ((TAPS == 9) ? 0 : 1)) * (size_t)PROW;
#pragma unroll
        for (int c = 0; c < (CHUNKS + 7) / 8; ++c) {
            int ch = w + c * 8;
            if (ch < CHUNKS)
                gld16(src + ch * 512 + l * 8, &sx[buf][ch * 512 + l * 8]);
        }
    };

    stage(0, 0);
    __syncthreads();
    for (int kc = 0; kc < KC; ++kc) {
        const int cur = kc & 1;
        if (kc + 1 < KC) stage(kc + 1, cur ^ 1);
        const bh8* wp = (const bh8*)wpk;
#pragma unroll
        for (int tap = 0; tap < TAPS; ++tap) {
            const int kh = (TAPS == 9) ? tap / 3 : 0;
            const int kw = (TAPS == 9) ? tap % 3 : 1;
            bh8 af[CT];
#pragma unroll
            for (int ct = 0; ct < CT; ++ct)
                af[ct] = wp[(((size_t)kc * TAPS + tap) * COT + (wc * CT + ct)) * 64 + l];
#pragma unroll
            for (int nt = 0; nt < 3; ++nt) {
                int tp = wt * 48 + nt * 16 + lc + kw;
                bh8 bf = *(const bh8*)&sx[cur][(kh * 98 + tp) * 32 + 8 * g];
#pragma unroll
                for (int ct = 0; ct < CT; ++ct)
                    acc[ct][nt] = __builtin_amdgcn_mfma_f32_16x16x32_bf16(
                        af[ct], bf, acc[ct][nt], 0, 0, 0);
            }
        }
        __syncthreads();
    }

    // ---- epilogue ----
#pragma unroll
    for (int ct = 0; ct < CT; ++ct) {
#pragma unroll
        for (int nt = 0; nt < 3; ++nt) {
            int tt = wt * 48 + nt * 16 + lc;
            if (OMODE == 2) {
                bh4 o;
#pragma unroll
                for (int j = 0; j < 4; ++j) {
                    int cog = (wc * CT + ct) * 16 + g * 4 + j;
                    float val = acc[ct][nt][j];
                    if (bias) val += bias[cog];
                    o[j] = (short)f2bf(val);
                }
                *(bh4*)&obf[(((size_t)b * 96 + v0) * 96 + tt) * COUT
                            + (wc * CT + ct) * 16 + g * 4] = o;
            } else if (OMODE == 0) {
#pragma unroll
                for (int j = 0; j < 4; ++j) {
                    int cog = (wc * CT + ct) * 16 + g * 4 + j;
                    float val = acc[ct][nt][j];
                    if (bias) val += bias[cog];
                    obf[(((size_t)b * COUT + cog) * 96 + v0) * 96 + tt] = f2bf(val);
                }
            } else {
#pragma unroll
                for (int j = 0; j < 4; ++j) {
                    int cog = (wc * CT + ct) * 16 + g * 4 + j;
                    size_t o = (((size_t)b * COUT + cog) * 96 + v0) * 96 + tt;
                    oacc[o] = xres[o] + acc[ct][nt][j];
                }
            }
        }
    }
}

// -------------------------------------------------------------------------
// transpose last two dims of compact planes
// -------------------------------------------------------------------------
__global__ __launch_bounds__(256) void transpose_vt_k(const ushort* __restrict__ in,
                                                      ushort* __restrict__ out,
                                                      int cs_in, int cn)
{
    __shared__ ushort tile[96][100];
    int b = blockIdx.x / cn, c = blockIdx.x % cn;
    size_t sbase = ((size_t)b * cs_in + c) * NVT;
    size_t dbase = (size_t)blockIdx.x * NVT;
    for (int n = threadIdx.x; n < NVT; n += 256) tile[n / 96][n % 96] = in[sbase + n];
    __syncthreads();
    for (int n = threadIdx.x; n < NVT; n += 256) out[dbase + n] = tile[n % 96][n / 96];
}

// -------------------------------------------------------------------------
// vAttn / tAttn via MFMA (swapped operands), unchanged core; av is written
// into the padded NC32 AVALL buffer at section `sec` (32-ch blocks).
// -------------------------------------------------------------------------
template<bool OVER_V>
__global__ __launch_bounds__(384) void attn_vt_mfma_k(const ushort* __restrict__ qkv,
                                                      ushort* __restrict__ avall,
                                                      int sec, int cstride, int cbase)
{
    __shared__ ushort sQT[96 * 40];
    __shared__ ushort sKT[96 * 40];
    __shared__ ushort sV[128 * 104];

    int b = blockIdx.x / 96, p = blockIdx.x % 96;
    int tid = threadIdx.x;
    int wv = tid >> 6, l = tid & 63;
    int g = l >> 4, lc = l & 15;

    const size_t base = ((size_t)b * cstride + cbase) * (size_t)NVT + (size_t)p * 96;

    for (int s = tid; s < 768; s += 384) {
        int hf = s / 384;
        int c  = (s % 384) / 12;
        int m  = s % 12;
        bh8 val = *(const bh8*)&qkv[base + (size_t)(hf * 32 + c) * NVT + 8 * m];
        ushort* dst = hf ? sKT : sQT;
#pragma unroll
        for (int u = 0; u < 8; ++u)
            dst[(8 * m + u) * 40 + c] = (ushort)val[u];
    }
    for (int s = tid; s < 1536; s += 384) {
        int c = s / 12, m = s % 12;
        *(bh8*)&sV[c * 104 + 8 * m] =
            *(const bh8*)&qkv[base + (size_t)(64 + c) * NVT + 8 * m];
    }
    __syncthreads();

    bh4 qlo = *(const bh4*)&sQT[(wv * 16 + lc) * 40 + 4 * g];
    bh4 qhi = *(const bh4*)&sQT[(wv * 16 + lc) * 40 + 4 * g + 16];
    bh8 bq = __builtin_shufflevector(qlo, qhi, 0, 1, 2, 3, 4, 5, 6, 7);

    f4 st[6];
#pragma unroll
    for (int mt = 0; mt < 6; ++mt) {
        bh4 alo = *(const bh4*)&sKT[(mt * 16 + lc) * 40 + 4 * g];
        bh4 ahi = *(const bh4*)&sKT[(mt * 16 + lc) * 40 + 4 * g + 16];
        bh8 ak = __builtin_shufflevector(alo, ahi, 0, 1, 2, 3, 4, 5, 6, 7);
        st[mt] = __builtin_amdgcn_mfma_f32_16x16x32_bf16(ak, bq,
                                                         (f4){0.f, 0.f, 0.f, 0.f},
                                                         0, 0, 0);
    }

    float mx = -1e30f;
#pragma unroll
    for (int mt = 0; mt < 6; ++mt)
#pragma unroll
        for (int j = 0; j < 4; ++j) mx = fmaxf(mx, st[mt][j]);
    mx = fmaxf(mx, __shfl_xor(mx, 16));
    mx = fmaxf(mx, __shfl_xor(mx, 32));
    float sum = 0.f;
#pragma unroll
    for (int mt = 0; mt < 6; ++mt)
#pragma unroll
        for (int j = 0; j < 4; ++j) {
            float e = __expf(st[mt][j] - mx);
            st[mt][j] = e;
            sum += e;
        }
    sum += __shfl_xor(sum, 16);
    sum += __shfl_xor(sum, 32);
    float inv = 1.f / sum;

    bh8 pf[3];
#pragma unroll
    for (int ks = 0; ks < 3; ++ks) {
        bh8 t;
#pragma unroll
        for (int i = 0; i < 8; ++i)
            t[i] = (short)f2bf(st[2 * ks + (i >> 2)][i & 3] * inv);
        pf[ks] = t;
    }

    f4 acc[8];
#pragma unroll
    for (int mt = 0; mt < 8; ++mt) acc[mt] = (f4){0.f, 0.f, 0.f, 0.f};
#pragma unroll
    for (int ks = 0; ks < 3; ++ks)
#pragma unroll
        for (int mt = 0; mt < 8; ++mt) {
            bh4 alo = *(const bh4*)&sV[(mt * 16 + lc) * 104 + ks * 32 + 4 * g];
            bh4 ahi = *(const bh4*)&sV[(mt * 16 + lc) * 104 + ks * 32 + 4 * g + 16];
            bh8 avf = __builtin_shufflevector(alo, ahi, 0, 1, 2, 3, 4, 5, 6, 7);
            acc[mt] = __builtin_amdgcn_mfma_f32_16x16x32_bf16(avf, pf[ks],
                                                              acc[mt], 0, 0, 0);
        }

    // write av into AVALL section: c = mt*16 + g*4 + j; block = sec + (mt>>1)
    int i = wv * 16 + lc;
#pragma unroll
    for (int mt = 0; mt < 8; ++mt) {
        int vv_ = OVER_V ? i : p;
        int tt_ = OVER_V ? p : i;
        bh4 o;
#pragma unroll
        for (int j = 0; j < 4; ++j) o[j] = (short)f2bf(acc[mt][j]);
        size_t off = ((((size_t)b * 16 + sec + (mt >> 1)) * 98 + 1 + vv_) * 98
                      + 1 + tt_) * 32 + 8 * g + 4 * (mt & 1);
        *(bh4*)&avall[off] = o;
    }
}

// -------------------------------------------------------------------------
// cAttn via MFMA: block per (v, cc, b); av written to AVALL sections 8..15.
// -------------------------------------------------------------------------
__global__ __launch_bounds__(256) void attn_c_k(const ushort* __restrict__ qc,
    const ushort* __restrict__ kc_, const ushort* __restrict__ vc,
    ushort* __restrict__ avall)
{
    __shared__ ushort sQ[64 * 104];
    __shared__ ushort sK[256 * 104];
    __shared__ ushort sV[96 * 264];
    __shared__ ushort sP[64 * 264];

    int v = blockIdx.x, cc = blockIdx.y, b = blockIdx.z;
    int c0 = cc * 64;
    int tid = threadIdx.x;
    int w = tid >> 6, l = tid & 63;
    int g = l >> 4, lc = l & 15;

    for (int s = tid; s < 64 * 12; s += 256) {
        int r = s / 12, sg = s % 12;
        *(bh8*)&sQ[r * 104 + sg * 8] =
            *(const bh8*)&qc[(((size_t)b * 256 + c0 + r) * 96 + v) * 96 + sg * 8];
    }
    for (int s = tid; s < 256 * 12; s += 256) {
        int r = s / 12, sg = s % 12;
        *(bh8*)&sK[r * 104 + sg * 8] =
            *(const bh8*)&kc_[(((size_t)b * 256 + r) * 96 + v) * 96 + sg * 8];
    }
    for (int s = tid; s < 96 * 32; s += 256) {
        int r = s / 32, sg = s % 32;
        *(bh8*)&sV[r * 264 + sg * 8] =
            *(const bh8*)&vc[(((size_t)b * 96 + v) * 96 + r) * 256 + sg * 8];
    }
    __syncthreads();

    f4 s16[16];
#pragma unroll
    for (int nt = 0; nt < 16; ++nt) s16[nt] = (f4){0.f, 0.f, 0.f, 0.f};
#pragma unroll
    for (int ks = 0; ks < 3; ++ks) {
        bh4 alo = *(const bh4*)&sQ[(w * 16 + lc) * 104 + ks * 32 + 4 * g];
        bh4 ahi = *(const bh4*)&sQ[(w * 16 + lc) * 104 + ks * 32 + 4 * g + 16];
        bh8 aq = __builtin_shufflevector(alo, ahi, 0, 1, 2, 3, 4, 5, 6, 7);
#pragma unroll
        for (int nt = 0; nt < 16; ++nt) {
            bh4 blo = *(const bh4*)&sK[(nt * 16 + lc) * 104 + ks * 32 + 4 * g];
            bh4 bhi = *(const bh4*)&sK[(nt * 16 + lc) * 104 + ks * 32 + 4 * g + 16];
            bh8 bk = __builtin_shufflevector(blo, bhi, 0, 1, 2, 3, 4, 5, 6, 7);
            s16[nt] = __builtin_amdgcn_mfma_f32_16x16x32_bf16(aq, bk, s16[nt], 0, 0, 0);
        }
    }
#pragma unroll
    for (int j = 0; j < 4; ++j) {
        float m = -1e30f;
#pragma unroll
        for (int nt = 0; nt < 16; ++nt) m = fmaxf(m, s16[nt][j]);
        m = fmaxf(m, __shfl_xor(m, 1));
        m = fmaxf(m, __shfl_xor(m, 2));
        m = fmaxf(m, __shfl_xor(m, 4));
        m = fmaxf(m, __shfl_xor(m, 8));
        float sum = 0.f;
#pragma unroll
        for (int nt = 0; nt < 16; ++nt) {
            float e = __expf(s16[nt][j] - m); s16[nt][j] = e; sum += e;
        }
        sum += __shfl_xor(sum, 1);
        sum += __shfl_xor(sum, 2);
        sum += __shfl_xor(sum, 4);
        sum += __shfl_xor(sum, 8);
        float inv = 1.f / sum;
#pragma unroll
        for (int nt = 0; nt < 16; ++nt)
            sP[(w * 16 + g * 4 + j) * 264 + nt * 16 + lc] = f2bf(s16[nt][j] * inv);
    }
    __syncthreads();

    f4 o6[6];
#pragma unroll
    for (int nt = 0; nt < 6; ++nt) o6[nt] = (f4){0.f, 0.f, 0.f, 0.f};
#pragma unroll
    for (int ks = 0; ks < 8; ++ks) {
        bh4 alo = *(const bh4*)&sP[(w * 16 + lc) * 264 + ks * 32 + 4 * g];
        bh4 ahi = *(const bh4*)&sP[(w * 16 + lc) * 264 + ks * 32 + 4 * g + 16];
        bh8 ap = __builtin_shufflevector(alo, ahi, 0, 1, 2, 3, 4, 5, 6, 7);
#pragma unroll
        for (int nt = 0; nt < 6; ++nt) {
            bh4 blo = *(const bh4*)&sV[(nt * 16 + lc) * 264 + ks * 32 + 4 * g];
            bh4 bhi = *(const bh4*)&sV[(nt * 16 + lc) * 264 + ks * 32 + 4 * g + 16];
            bh8 bv = __builtin_shufflevector(blo, bhi, 0, 1, 2, 3, 4, 5, 6, 7);
            o6[nt] = __builtin_amdgcn_mfma_f32_16x16x32_bf16(ap, bv, o6[nt], 0, 0, 0);
        }
    }
    // store: c = c0 + w*16 + g*4 + j -> AVALL block 8 + cc*2 + (w>>1)
#pragma unroll
    for (int nt = 0; nt < 6; ++nt) {
        int t = nt * 16 + lc;
        bh4 o;
#pragma unroll
        for (int j = 0; j < 4; ++j) o[j] = (short)f2bf(o6[nt][j]);
        size_t off = ((((size_t)b * 16 + 8 + cc * 2 + (w >> 1)) * 98 + 1 + v) * 98
                      + 1 + t) * 32 + 8 * g + 4 * (w & 1);
        *(bh4*)&avall[off] = o;
    }
}

// -------------------------------------------------------------------------
extern "C" void kernel_launch(void* const* d_in, const int* in_sizes, int n_in,
                              void* d_out, int out_size, void* d_ws, size_t ws_size,
                              hipStream_t stream)
{
    const float* x     = (const float*)d_in[0];
    const float* v_wq  = (const float*)d_in[1];
    const float* v_wk  = (const float*)d_in[2];
    const float* v_wv  = (const float*)d_in[3];
    const float* v_wo  = (const float*)d_in[4];
    const float* v_sig = (const float*)d_in[5];
    const float* t_wq  = (const float*)d_in[6];
    const float* t_wk  = (const float*)d_in[7];
    const float* t_wv  = (const float*)d_in[8];
    const float* t_wo  = (const float*)d_in[9];
    const float* t_sig = (const float*)d_in[10];
    const float* c_wq  = (const float*)d_in[11];
    const float* c_bq  = (const float*)d_in[12];
    const float* c_wk  = (const float*)d_in[13];
    const float* c_bk  = (const float*)d_in[14];
    const float* c_wv  = (const float*)d_in[15];
    const float* c_bv  = (const float*)d_in[16];
    const float* c_wo  = (const float*)d_in[17];
    const float* c_sig = (const float*)d_in[18];

    float*  out = (float*)d_out;
    ushort* ws  = (ushort*)d_ws;

    // ---- workspace layout (ushort units) ----
    const size_t X32   = 0;                        // [8][8][98][98][32] + pad
    const size_t AVL   = X32 + 19685376;           // [8][16][98][98][32] + pad
    const size_t POOL  = AVL + 39354368;           // 42,467,328 shorts
    const size_t QKVV  = POOL;                     // [8][192][9216]
    const size_t QKVVT = POOL + 14155776;
    const size_t QKVT_ = POOL + 28311552;
    const size_t QC    = POOL;                     // alias (vt buffers dead)
    const size_t KCB   = POOL + 18874368;
    const size_t VCT   = POOL + 42467328;          // [8][96][96][256]
    const size_t PK    = VCT + 18874368;
    const size_t PK_PV  = PK;                      // 8*9*12*512 = 442368
    const size_t PK_PT  = PK_PV + 442368;
    const size_t PK_CQ  = PK_PT + 442368;          // 8*1*16*512 = 65536
    const size_t PK_CK  = PK_CQ + 65536;
    const size_t PK_CV  = PK_CK + 65536;
    const size_t PK_FIN = PK_CV + 65536;           // 16*9*16*512 = 1179648

    // pads + layout conversion
    pad_zero_k<<<192, 256, 0, stream>>>(ws + X32, ws + AVL);
    cvt_x32_k<<<dim3(96, 8, BB), 256, 0, stream>>>(x, ws + X32);

    auto pack = [&](const float* w, size_t dst, int cin, int taps, int csrc,
                    int cobase, int cot, int kcb, const float* sc) {
        int total = (cin >> 5) * taps * csrc * 32;
        wpack_k<<<(total + 255) / 256, 256, 0, stream>>>(w, ws + dst, cin, taps,
                                                          csrc, cobase, cot, kcb, sc);
    };
    pack(v_wq, PK_PV, 256, 9, 32, 0, 12, 0, nullptr);
    pack(v_wk, PK_PV, 256, 9, 32, 32, 12, 0, nullptr);
    pack(v_wv, PK_PV, 256, 9, 128, 64, 12, 0, nullptr);
    pack(t_wq, PK_PT, 256, 9, 32, 0, 12, 0, nullptr);
    pack(t_wk, PK_PT, 256, 9, 32, 32, 12, 0, nullptr);
    pack(t_wv, PK_PT, 256, 9, 128, 64, 12, 0, nullptr);
    pack(c_wq, PK_CQ, 256, 1, 256, 0, 16, 0, nullptr);
    pack(c_wk, PK_CK, 256, 1, 256, 0, 16, 0, nullptr);
    pack(c_wv, PK_CV, 256, 1, 256, 0, 16, 0, nullptr);
    // fused final conv: CIN concat [av_v(128)|av_t(128)|av_c(256)], sigma folded
    pack(v_wo, PK_FIN, 128, 9, 256, 0, 16, 0, v_sig);
    pack(t_wo, PK_FIN, 128, 9, 256, 0, 16, 4, t_sig);
    pack(c_wo, PK_FIN, 256, 9, 256, 0, 16, 8, c_sig);

    dim3 cgrid(96, BB);

    // ---- vAttn ----
    conv_mfma<9, 3, 0><<<cgrid, 512, 0, stream>>>(
        ws + X32, ws + PK_PV, ws + QKVV, nullptr, nullptr, nullptr, 8);
    transpose_vt_k<<<BB * 192, 256, 0, stream>>>(ws + QKVV, ws + QKVVT, 192, 192);
    attn_vt_mfma_k<true><<<BB * 96, 384, 0, stream>>>(ws + QKVVT, ws + AVL, 0, 192, 0);

    // ---- tAttn ----
    conv_mfma<9, 3, 0><<<cgrid, 512, 0, stream>>>(
        ws + X32, ws + PK_PT, ws + QKVT_, nullptr, nullptr, nullptr, 8);
    attn_vt_mfma_k<false><<<BB * 96, 384, 0, stream>>>(ws + QKVT_, ws + AVL, 4, 192, 0);

    // ---- cAttn ----
    conv_mfma<1, 4, 0><<<cgrid, 512, 0, stream>>>(
        ws + X32, ws + PK_CQ, ws + QC, nullptr, nullptr, c_bq, 8);
    conv_mfma<1, 4, 0><<<cgrid, 512, 0, stream>>>(
        ws + X32, ws + PK_CK, ws + KCB, nullptr, nullptr, c_bk, 8);
    conv_mfma<1, 4, 2><<<cgrid, 512, 0, stream>>>(
        ws + X32, ws + PK_CV, ws + VCT, nullptr, nullptr, c_bv, 8);
    attn_c_k<<<dim3(96, 4, BB), 256, 0, stream>>>(ws + QC, ws + KCB, ws + VCT,
                                                  ws + AVL);

    // ---- fused output projection + residual: out = x + conv(AVALL) ----
    conv_mfma<9, 4, 5><<<cgrid, 512, 0, stream>>>(
        ws + AVL, ws + PK_FIN, nullptr, x, out, nullptr, 16);
}